// Round 14
// baseline (431.202 us; speedup 1.0000x reference)
//
#include <hip/hip_runtime.h>
#include <hip/hip_bf16.h>
#include <math.h>

#define BB 2
#define SS 1024
#define DIM 2048
#define HH 16
#define QR 1536
#define KVR 512
#define DN 128
#define DR 64
#define DV 128
#define QKD 192
#define NT (BB*SS)

typedef __attribute__((ext_vector_type(8))) short bhalf8;
typedef __attribute__((ext_vector_type(4))) float f32x4;

__device__ __forceinline__ unsigned short f2b(float f) {
  union { float f; unsigned u; } v; v.f = f;
  unsigned r = v.u + 0x7fffu + ((v.u >> 16) & 1u);
  return (unsigned short)(r >> 16);
}
__device__ __forceinline__ float b2f(unsigned short h) {
  union { unsigned u; float f; } v; v.u = ((unsigned)h) << 16;
  return v.f;
}

__device__ __forceinline__ void gload16(const void* g, void* l) {
  __builtin_amdgcn_global_load_lds((const __attribute__((address_space(1))) void*)g,
                                   (__attribute__((address_space(3))) void*)l, 16, 0, 0);
}

// ---------------- plain f32 -> bf16 convert ----------------
__global__ void cvt_k(const float* __restrict__ in, unsigned short* __restrict__ out, long n4) {
  long i = (long)blockIdx.x * 256 + threadIdx.x;
  if (i >= n4) return;
  float4 v = ((const float4*)in)[i];
  ushort4 o; o.x = f2b(v.x); o.y = f2b(v.y); o.z = f2b(v.z); o.w = f2b(v.w);
  ((ushort4*)out)[i] = o;
}

// ---------------- fused conversions: xb, wqa, wkva, wkT ----------------
__global__ void cvtall_k(const float* __restrict__ x,     unsigned short* __restrict__ xb,
                         const float* __restrict__ wqa,   unsigned short* __restrict__ wqab,
                         const float* __restrict__ wkva,  unsigned short* __restrict__ wkvab,
                         const float* __restrict__ wk,    unsigned short* __restrict__ wkT)
{
  long i = (long)blockIdx.x * 256 + threadIdx.x;
  const float* in; unsigned short* out; long j;
  if (i < 1048576)      { in = x;    out = xb;    j = i; }
  else if (i < 1835008) { in = wqa;  out = wqab;  j = i - 1048576; }
  else if (i < 2129920) { in = wkva; out = wkvab; j = i - 1835008; }
  else {
    j = i - 2129920;
    if (j >= 262144) return;
    long e = j * 4;
    int d = (int)(e & 127), c = (int)((e >> 7) & 511), h = (int)(e >> 16);
    ushort4 o;
    o.x = f2b(wk[((long)h * 256 + d + 0) * 512 + c]);
    o.y = f2b(wk[((long)h * 256 + d + 1) * 512 + c]);
    o.z = f2b(wk[((long)h * 256 + d + 2) * 512 + c]);
    o.w = f2b(wk[((long)h * 256 + d + 3) * 512 + c]);
    ((ushort4*)wkT)[j] = o;
    return;
  }
  float4 v = ((const float4*)in)[j];
  ushort4 o; o.x = f2b(v.x); o.y = f2b(v.y); o.z = f2b(v.z); o.w = f2b(v.w);
  ((ushort4*)out)[j] = o;
}

// ---------------- fused post-flash conversions: wkb, wo ----------------
__global__ void cvt2_k(const float* __restrict__ wk, unsigned short* __restrict__ wkb,
                       const float* __restrict__ wo, unsigned short* __restrict__ wob)
{
  long i = (long)blockIdx.x * 256 + threadIdx.x;
  const float* in; unsigned short* out; long j;
  if (i < 524288) { in = wk; out = wkb; j = i; }
  else            { in = wo; out = wob; j = i - 524288; if (j >= 1048576) return; }
  float4 v = ((const float4*)in)[j];
  ushort4 o; o.x = f2b(v.x); o.y = f2b(v.y); o.z = f2b(v.z); o.w = f2b(v.w);
  ((ushort4*)out)[j] = o;
}

// V^T tile-major, UNSWIZZLED: kt[b][st(32)][vc][kvl] = kvn[b][st*32+kvl][vc]
// (input kcatb is col-swizzled by (t&7)<<3 on the read side)
__global__ void kcT_k(const unsigned short* __restrict__ kc, unsigned short* __restrict__ kt) {
  int idx = blockIdx.x * 256 + threadIdx.x;    // 2*512*1024
  int t = idx & 1023, c = (idx >> 10) & 511, b = idx >> 19;
  int csrc = c ^ ((t & 7) << 3);
  kt[(((long)b * 32 + (t >> 5)) * 512 + c) * 32 + (t & 31)] =
      kc[((long)b * SS + t) * 576 + csrc];
}

// ---------------- MFMA GEMM 128x128 (kept for q_abs) ----------------
template<int OBF>
__global__ __launch_bounds__(256) void gemm_mfma(
    const unsigned short* __restrict__ A, int lda, long sA,
    const unsigned short* __restrict__ B, int ldb, long sB,
    void* __restrict__ C, int ldc, long sC,
    int M, int N, int K, const float* __restrict__ bias)
{
  const int bx = blockIdx.x, by = blockIdx.y, bz = blockIdx.z;
  const int m0 = by * 128, n0 = bx * 128;
  A += (long)bz * sA;
  B += (long)bz * sB;

  __shared__ unsigned short As[4096];
  __shared__ unsigned short Bs[4096];
  const int tid = threadIdx.x, l = tid & 63, w = tid >> 6;
  const int wr = w >> 1, wc = w & 1;
  const int rA = l >> 2;
  const int c8 = (((l & 3) ^ ((l >> 2) & 3)) << 3);

  f32x4 acc[4][4] = {};

  const unsigned short* Ab0 = A + (long)(m0 + w * 16 + rA) * lda + c8;
  const unsigned short* Ab1 = Ab0 + (long)64 * lda;
  int nb0 = n0 + w * 16 + rA;      if (nb0 > N - 1) nb0 = N - 1;
  int nb1 = n0 + 64 + w * 16 + rA; if (nb1 > N - 1) nb1 = N - 1;
  const unsigned short* Bb0 = B + (long)nb0 * ldb + c8;
  const unsigned short* Bb1 = B + (long)nb1 * ldb + c8;

  const int ko = (((l >> 4) ^ (l & 3)) << 3);

  for (int k0 = 0; k0 < K; k0 += 32) {
    gload16(Ab0 + k0, &As[w * 512]);
    gload16(Ab1 + k0, &As[(w + 4) * 512]);
    gload16(Bb0 + k0, &Bs[w * 512]);
    gload16(Bb1 + k0, &Bs[(w + 4) * 512]);
    __syncthreads();
    bhalf8 af[4], bv[4];
#pragma unroll
    for (int m = 0; m < 4; ++m) {
      af[m] = *(const bhalf8*)&As[(wr * 64 + m * 16 + (l & 15)) * 32 + ko];
      bv[m] = *(const bhalf8*)&Bs[(wc * 64 + m * 16 + (l & 15)) * 32 + ko];
    }
#pragma unroll
    for (int m = 0; m < 4; ++m)
#pragma unroll
      for (int n = 0; n < 4; ++n)
        acc[m][n] = __builtin_amdgcn_mfma_f32_16x16x32_bf16(af[m], bv[n], acc[m][n], 0, 0, 0);
    __syncthreads();
  }

  const int ro = (l >> 4) << 2;
  const int co = l & 15;
#pragma unroll
  for (int m = 0; m < 4; ++m) {
    int row = m0 + wr * 64 + m * 16 + ro;
#pragma unroll
    for (int n = 0; n < 4; ++n) {
      int col = n0 + wc * 64 + n * 16 + co;
      if (col < N) {
        float bvl = bias ? bias[col] : 0.f;
#pragma unroll
        for (int r = 0; r < 4; ++r) {
          float v = acc[m][n][r] + bvl;
          long off = (long)bz * sC + (long)(row + r) * ldc + col;
          if (OBF) ((unsigned short*)C)[off] = f2b(v);
          else     ((float*)C)[off] = v;
        }
      }
    }
  }
}

// ---------------- MFMA GEMM 64x128 tile (high-occupancy variant) ----------------
template<int OBF, int ROPE, int SPLIT>
__global__ __launch_bounds__(256) void gemm64(
    const unsigned short* __restrict__ A, int lda, long sA,
    const unsigned short* __restrict__ B, int ldb, long sB,
    void* __restrict__ C, int ldc, long sC,
    int M, int N, int K, const float* __restrict__ bias,
    unsigned short* __restrict__ qcat, const float* __restrict__ cosT,
    const float* __restrict__ sinT,
    float* __restrict__ C2, const float* __restrict__ bias2)
{
  const int bx = blockIdx.x, by = blockIdx.y, bz = blockIdx.z;
  const int m0 = by * 64, n0 = bx * 128;
  A += (long)bz * sA;
  B += (long)bz * sB;

  __shared__ unsigned short As[2048];
  __shared__ unsigned short Bs[4096];
  const int tid = threadIdx.x, l = tid & 63, w = tid >> 6;
  const int rA = l >> 2;
  const int c8 = (((l & 3) ^ ((l >> 2) & 3)) << 3);

  f32x4 acc[8] = {};

  const unsigned short* Ab0 = A + (long)(m0 + w * 16 + rA) * lda + c8;
  int nb0 = n0 + w * 16 + rA;      if (nb0 > N - 1) nb0 = N - 1;
  int nb1 = n0 + 64 + w * 16 + rA; if (nb1 > N - 1) nb1 = N - 1;
  const unsigned short* Bb0 = B + (long)nb0 * ldb + c8;
  const unsigned short* Bb1 = B + (long)nb1 * ldb + c8;

  const int ko = (((l >> 4) ^ (l & 3)) << 3);

  for (int k0 = 0; k0 < K; k0 += 32) {
    gload16(Ab0 + k0, &As[w * 512]);
    gload16(Bb0 + k0, &Bs[w * 512]);
    gload16(Bb1 + k0, &Bs[(w + 4) * 512]);
    __syncthreads();
    bhalf8 af = *(const bhalf8*)&As[(w * 16 + (l & 15)) * 32 + ko];
    bhalf8 bv[8];
#pragma unroll
    for (int n = 0; n < 8; ++n)
      bv[n] = *(const bhalf8*)&Bs[(n * 16 + (l & 15)) * 32 + ko];
#pragma unroll
    for (int n = 0; n < 8; ++n)
      acc[n] = __builtin_amdgcn_mfma_f32_16x16x32_bf16(af, bv[n], acc[n], 0, 0, 0);
    __syncthreads();
  }

  const int ro = (l >> 4) << 2;
  const int co = l & 15;
#pragma unroll
  for (int r = 0; r < 4; ++r) {
    int row = m0 + w * 16 + ro + r;
    float v[8];
#pragma unroll
    for (int n = 0; n < 8; ++n) {
      int col = n0 + n * 16 + co;
      float bv2 = 0.f;
      if (SPLIT) bv2 = (col < QR) ? bias[col] : ((col < QR + 576) ? bias2[col - QR] : 0.f);
      else if (bias && col < N) bv2 = bias[col];
      v[n] = acc[n][r] + bv2;
    }
    if (ROPE) {
      int s = row & (SS - 1);
#pragma unroll
      for (int n = 0; n < 8; ++n) {
        int col0 = n0 + n * 16;
        int cm0 = col0 % 192;
        if (cm0 < 128) {
          ((unsigned short*)C)[(long)row * ldc + col0 + co] = f2b(v[n]);
        } else if (cm0 == 128 || cm0 == 144) {
          int d = cm0 - 128 + co;
          float cl = cosT[s * DR + d],      sl = sinT[s * DR + d];
          float ch = cosT[s * DR + d + 32], sh = sinT[s * DR + d + 32];
          float o_lo = v[n] * cl - v[n + 2] * sl;
          float o_hi = v[n + 2] * ch + v[n] * sh;
          unsigned short* qp = qcat + ((long)(col0 / 192) * NT + row) * 576 + 512;
          qp[d]      = f2b(o_lo);
          qp[d + 32] = f2b(o_hi);
        }
      }
    } else if (SPLIT) {
#pragma unroll
      for (int n = 0; n < 8; ++n) {
        int col = n0 + n * 16 + co;
        if (col < QR)            ((float*)C)[(long)row * ldc + col] = v[n];
        else if (col < QR + 576) C2[(long)row * 576 + (col - QR)] = v[n];
      }
    } else {
#pragma unroll
      for (int n = 0; n < 8; ++n) {
        int col = n0 + n * 16 + co;
        if (col < N) {
          long off = (long)bz * sC + (long)row * ldc + col;
          if (OBF) ((unsigned short*)C)[off] = f2b(v[n]);
          else     ((float*)C)[off] = v[n];
        }
      }
    }
  }
}

// ---------------- RMSNorm fp32 -> bf16 (optional col swizzle by row) ----------------
template<int SWZ>
__global__ void rmsnorm_k(const float* __restrict__ in, int ldin,
                          unsigned short* __restrict__ out, int ldout,
                          const float* __restrict__ w, int N) {
  long row = blockIdx.x;
  const float* x = in + row * ldin;
  unsigned short* y = out + row * ldout;
  float ss = 0.f;
  for (int i = threadIdx.x; i < N; i += 256) { float u = x[i]; ss += u * u; }
  for (int o = 32; o > 0; o >>= 1) ss += __shfl_down(ss, o);
  __shared__ float red[4];
  int lane = threadIdx.x & 63, wid = threadIdx.x >> 6;
  if (lane == 0) red[wid] = ss;
  __syncthreads();
  float r = rsqrtf((red[0] + red[1] + red[2] + red[3]) / (float)N + 1e-6f);
  int sw = SWZ ? (((int)row & 7) << 3) : 0;
  for (int i = threadIdx.x; i < N; i += 256) y[i ^ sw] = f2b(x[i] * r * w[i]);
}

// ---------------- RoPE on k_pe -> kcatb cols 512..575 (swizzled) ----------------
__global__ void rope_k_k(const float* __restrict__ kv, unsigned short* __restrict__ kc,
                         const float* __restrict__ cosT, const float* __restrict__ sinT) {
  int idx = blockIdx.x * 256 + threadIdx.x;
  int d = idx & 31, t = idx >> 5, s = t & (SS - 1);
  const float* p = kv + (long)t * 576 + 512;
  float x1 = p[d], x2 = p[d + 32];
  float c1 = cosT[s * DR + d],      s1 = sinT[s * DR + d];
  float c2 = cosT[s * DR + 32 + d], s2 = sinT[s * DR + 32 + d];
  unsigned short* o = kc + (long)t * 576;
  int sw = (t & 7) << 3;
  o[(512 + d) ^ sw]      = f2b(x1 * c1 - x2 * s1);
  o[(512 + d + 32) ^ sw] = f2b(x2 * c2 + x1 * s2);
}

// ---------------- fused flash attention v7: K double-buffer + V direct-from-L2 ----------------
// 512 blocks, flat-descending qt (dispatch backfill).  4 waves x 16 q-rows.
// Per step: issue K(t+1)->Kn | QK^T(Kc) | softmax | PV (V read direct, coalesced 1KB) | bar.
// LDS: K0/K1 [32][1152B] + P[4][16][64B] = 77,824 B -> 2 blocks/CU.
__global__ __launch_bounds__(256) void flash_k(
    const unsigned short* __restrict__ qcat,   // [16][NT][576] linear
    const unsigned short* __restrict__ kcb,    // [B][S][576]  col-swizzled ^((t&7)<<3)
    const unsigned short* __restrict__ kct,    // [B][32][512][32] tile-major, linear
    unsigned short* __restrict__ omid)         // [16][NT][512]
{
  __shared__ __align__(16) char lds[77824];
  char* K0 = lds;                // 36,864 B
  char* K1 = lds + 36864;        // 36,864 B
  char* Pl = lds + 73728;        //  4,096 B

  const int bid = blockIdx.x;
  const int qt = 15 - (bid >> 5);
  const int bh = bid & 31;
  const int b = bh & 1, h = bh >> 1;
  const int tid = threadIdx.x, l = tid & 63, w = tid >> 6;
  const int lo = l & 15, hi = l >> 4;

  const unsigned short* qrow =
      qcat + ((long)h * NT + b * SS + qt * 64 + w * 16 + lo) * 576 + hi * 8;
  bhalf8 qf[18];
#pragma unroll
  for (int ks = 0; ks < 18; ++ks) qf[ks] = *(const bhalf8*)(qrow + ks * 32);

  f32x4 po[32] = {};                  // O[q=hi*4+r][vc=nv*16+lo]
  float mrow[4] = {-1e30f, -1e30f, -1e30f, -1e30f};
  float lrow[4] = {0.f, 0.f, 0.f, 0.f};
  const float sc = 0.07216878364870323f;   // 1/sqrt(192)
  char* Pwv = Pl + w * 1024;

  const char* ksrc = (const char*)kcb + (long)b * SS * 1152;
  const char* vsrc = (const char*)kct + (long)b * 32 * 32768;
  const int smax = 2 * qt + 1;

  // prologue: stage K(0) into K0
#pragma unroll
  for (int i = 0; i < 9; ++i) {
    int off = (w + i * 4) * 1024 + l * 16;
    gload16(ksrc + off, K0 + off);
  }
  __syncthreads();

  char* Kc = K0;
  char* Kn = K1;

  for (int st = 0; st <= smax; ++st) {
    // issue next K tile into the other buffer (hidden under this step's compute)
    if (st < smax) {
      const char* kn = ksrc + 36864;
#pragma unroll
      for (int i = 0; i < 9; ++i) {
        int off = (w + i * 4) * 1024 + l * 16;
        gload16(kn + off, Kn + off);
      }
    }

    // QK^T from Kc
    f32x4 sa[2] = {};
    __builtin_amdgcn_s_setprio(1);
#pragma unroll
    for (int ks = 0; ks < 18; ++ks) {
#pragma unroll
      for (int n = 0; n < 2; ++n) {
        int kv = n * 16 + lo;
        bhalf8 kf = *(const bhalf8*)(Kc + kv * 1152 + (((ks * 4 + hi) ^ (kv & 7)) << 4));
        sa[n] = __builtin_amdgcn_mfma_f32_16x16x32_bf16(qf[ks], kf, sa[n], 0, 0, 0);
      }
    }
    __builtin_amdgcn_s_setprio(0);
    // scale + causal mask
    if (st >= 2 * qt) {
      const int kv0 = st * 32;
#pragma unroll
      for (int n = 0; n < 2; ++n) {
        int kvg = kv0 + n * 16 + lo;
#pragma unroll
        for (int r = 0; r < 4; ++r) {
          int qg = qt * 64 + w * 16 + hi * 4 + r;
          sa[n][r] = (kvg > qg) ? -1e30f : sa[n][r] * sc;
        }
      }
    } else {
#pragma unroll
      for (int n = 0; n < 2; ++n)
#pragma unroll
        for (int r = 0; r < 4; ++r) sa[n][r] *= sc;
    }
    // row max
    float pmax[4];
#pragma unroll
    for (int r = 0; r < 4; ++r) {
      float v = fmaxf(sa[0][r], sa[1][r]);
      v = fmaxf(v, __shfl_xor(v, 1));
      v = fmaxf(v, __shfl_xor(v, 2));
      v = fmaxf(v, __shfl_xor(v, 4));
      v = fmaxf(v, __shfl_xor(v, 8));
      pmax[r] = v;
    }
    // defer-max rescale (THR=8)
    bool need = false;
#pragma unroll
    for (int r = 0; r < 4; ++r) need |= (pmax[r] > mrow[r] + 8.f);
    if (__any(need)) {
#pragma unroll
      for (int r = 0; r < 4; ++r) {
        float mn = fmaxf(mrow[r], pmax[r]);
        float fac = __expf(mrow[r] - mn);
        mrow[r] = mn;
        lrow[r] *= fac;
#pragma unroll
        for (int nv = 0; nv < 32; ++nv) po[nv][r] *= fac;
      }
    }
    // P = exp(S - m), row sums
    float rs[4] = {0.f, 0.f, 0.f, 0.f};
#pragma unroll
    for (int n = 0; n < 2; ++n)
#pragma unroll
      for (int r = 0; r < 4; ++r) {
        float p = __expf(sa[n][r] - mrow[r]);
        sa[n][r] = p;
        rs[r] += p;
      }
#pragma unroll
    for (int r = 0; r < 4; ++r) {
      float v = rs[r];
      v += __shfl_xor(v, 1); v += __shfl_xor(v, 2);
      v += __shfl_xor(v, 4); v += __shfl_xor(v, 8);
      lrow[r] += v;
    }
    // P -> bf16 -> wave-private LDS
#pragma unroll
    for (int n = 0; n < 2; ++n)
#pragma unroll
      for (int r = 0; r < 4; ++r) {
        int q = hi * 4 + r, kv = n * 16 + lo;
        *(unsigned short*)(Pwv + q * 64 + ((kv * 2) ^ ((q & 3) << 4))) = f2b(sa[n][r]);
      }
    // PV: V read directly from global (coalesced 1KB per 64-lane load), 4 groups of 8
    bhalf8 pa = *(const bhalf8*)(Pwv + lo * 64 + ((hi * 16) ^ ((lo & 3) << 4)));
    __builtin_amdgcn_s_setprio(1);
#pragma unroll
    for (int g = 0; g < 4; ++g) {
      bhalf8 vb[8];
#pragma unroll
      for (int j = 0; j < 8; ++j) {
        int vc = (g * 8 + j) * 16 + lo;
        vb[j] = *(const bhalf8*)(vsrc + (long)vc * 64 + hi * 16);
      }
#pragma unroll
      for (int j = 0; j < 8; ++j)
        po[g * 8 + j] = __builtin_amdgcn_mfma_f32_16x16x32_bf16(pa, vb[j], po[g * 8 + j], 0, 0, 0);
    }
    __builtin_amdgcn_s_setprio(0);
    __syncthreads();
    { char* t = Kc; Kc = Kn; Kn = t; }
    ksrc += 36864; vsrc += 32768;
  }

  // epilogue
  unsigned short* orow = omid + ((long)h * NT + b * SS + qt * 64) * 512;
  float inv[4];
#pragma unroll
  for (int r = 0; r < 4; ++r) inv[r] = 1.f / lrow[r];
#pragma unroll
  for (int nv = 0; nv < 32; ++nv)
#pragma unroll
    for (int r = 0; r < 4; ++r) {
      int q = w * 16 + hi * 4 + r;
      orow[(long)q * 512 + nv * 16 + lo] = f2b(po[nv][r] * inv[r]);
    }
}

// ---------------- launch ----------------
extern "C" void kernel_launch(void* const* d_in, const int* in_sizes, int n_in,
                              void* d_out, int out_size, void* d_ws, size_t ws_size,
                              hipStream_t stream) {
  const float* x        = (const float*)d_in[0];
  const float* wq_a_w   = (const float*)d_in[2];
  const float* wq_a_b   = (const float*)d_in[3];
  const float* q_norm_w = (const float*)d_in[4];
  const float* wq_b_w   = (const float*)d_in[5];
  const float* wq_b_b   = (const float*)d_in[6];
  const float* wkv_a_w  = (const float*)d_in[7];
  const float* wkv_a_b  = (const float*)d_in[8];
  const float* kv_norm_w= (const float*)d_in[9];
  const float* wk_b_w   = (const float*)d_in[10];
  const float* wo_w     = (const float*)d_in[11];
  const float* wo_bias  = (const float*)d_in[12];
  const float* cosT     = (const float*)d_in[13];
  const float* sinT     = (const float*)d_in[14];
  float* out = (float*)d_out;

  char* W = (char*)d_ws;
  // core live-through-flash buffers
  unsigned short* kcatb  = (unsigned short*)(W + 0);          // 2.36 MB [B*S][576] swz
  unsigned short* kcatT  = (unsigned short*)(W + 2359296);    // 2.10 MB [B][32][512][32]
  unsigned short* qcat   = (unsigned short*)(W + 4456448);    // 37.75 MB [16][NT][576]
  unsigned short* o_mid  = (unsigned short*)(W + 42205184);   // 33.55 MB [16][NT][512]
  // pre-flash aliases in qcat region — ALL dead before q_b writes qcat pe cols:
  unsigned short* xb     = (unsigned short*)(W + 4456448);    // 8.39 MB (dead after qkv_a)
  unsigned short* wqa_b  = (unsigned short*)(W + 12845056);   // 6.29 MB } contiguous: combined
  unsigned short* wkva_b = (unsigned short*)(W + 19136512);   // 2.36 MB } B of 2112 rows
  float*          kv_f32 = (float*)        (W + 21495808);    // 4.72 MB (dead after rope_k)
  // pre-flash aliases in o_mid region (dead before flash writes o_mid)
  unsigned short* qb     = (unsigned short*)(W + 42205184);   // 12.58 MB [NT][3072]
  unsigned short* wkT_b  = (unsigned short*)(W + 54788096);   // 2.10 MB
  float*          qn_f32 = (float*)        (W + 56885248);    // 12.58 MB
  unsigned short* wqb_b  = (unsigned short*)(W + 56885248);   // 9.44 MB (overlays qn after rmsnorm_q)
  unsigned short* qnb    = (unsigned short*)(W + 69468160);   // 6.29 MB (end 75,759,616)
  // post-flash aliases in qcat region (qcat dead after flash)
  unsigned short* wkb_b  = (unsigned short*)(W + 4456448);    // 4.19 MB
  unsigned short* ohead  = (unsigned short*)(W + 8650752);    // 8.39 MB [NT][2048]
  unsigned short* wo_b16 = (unsigned short*)(W + 17039360);   // 8.39 MB

  // fused conversions (xb, wqa, wkva, wkT); wqb converted later into dead qn slot
  cvtall_k<<<9344, 256, 0, stream>>>(x, xb, wq_a_w, wqa_b, wkv_a_w, wkva_b, wk_b_w, wkT_b);

  // combined q_a + kv_a: [qn | kv] = x @ [wqa; wkva]^T  (N=2112, split epilogue, 64x128 tiles)
  gemm64<0,0,1><<<dim3(17, NT/64, 1), 256, 0, stream>>>(
      xb, DIM, 0, wqa_b, DIM, 0, qn_f32, QR, 0, NT, QR + 576, DIM, wq_a_b,
      nullptr, nullptr, nullptr, kv_f32, wkv_a_b);

  // kv chain (kills xb / wkva / kv_f32 before q_b touches qcat)
  rmsnorm_k<1><<<NT, 256, 0, stream>>>(kv_f32, 576, kcatb, 576, kv_norm_w, KVR);
  rope_k_k<<<256, 256, 0, stream>>>(kv_f32, kcatb, cosT, sinT);
  kcT_k<<<4096, 256, 0, stream>>>(kcatb, kcatT);

  // q path
  rmsnorm_k<0><<<NT, 256, 0, stream>>>(qn_f32, QR, qnb, QR, q_norm_w, QR);
  cvt_k<<<4608, 256, 0, stream>>>(wq_b_w, wqb_b, (long)3072 * QR / 4);   // into dead qn slot
  // q_b: qb = qnb @ wq_b^T (bf16); pe windows rope'd straight into qcat cols 512..575
  gemm64<1,1,0><<<dim3(3072/128, NT/64, 1), 256, 0, stream>>>(
      qnb, QR, 0, wqb_b, QR, 0, qb, 3072, 0, NT, 3072, QR, wq_b_b,
      qcat, cosT, sinT, nullptr, nullptr);

  // q_abs for all 16 heads: qcat[z][:, :512] = q_nope_z @ wkT[z]^T  (128x128 path)
  gemm_mfma<1><<<dim3(4, NT/128, 16), 256, 0, stream>>>(
      qb, 3072, QKD, wkT_b, DN, (long)KVR * DN,
      qcat, 576, (long)NT * 576, NT, KVR, DN, nullptr);

  // fused attention, all heads, one dispatch
  flash_k<<<512, 256, 0, stream>>>(qcat, kcatb, kcatT, o_mid);

  // post-flash conversions (wkb, wo) in one kernel  [qcat dead]
  cvt2_k<<<6144, 256, 0, stream>>>(wk_b_w, wkb_b, wo_w, wo_b16);

  // V-absorb: ohead[:, z*128..] = o_mid[z] @ wkv_b_v[z]^T  (64x128 tiles)
  gemm64<1,0,0><<<dim3(1, NT/64, 16), 256, 0, stream>>>(
      o_mid, KVR, (long)NT * KVR,
      wkb_b + (long)DN * KVR, KVR, (long)256 * KVR,
      ohead, HH * DV, DV, NT, DV, KVR, nullptr,
      nullptr, nullptr, nullptr, nullptr, nullptr);

  // out = o_head @ wo^T + b (fp32, 64x128 tiles)
  gemm64<0,0,0><<<dim3(DIM/128, NT/64, 1), 256, 0, stream>>>(
      ohead, 2048, 0, wo_b16, 2048, 0, out, DIM, 0, NT, DIM, 2048, wo_bias,
      nullptr, nullptr, nullptr, nullptr, nullptr);
}

// Round 15
// 332.821 us; speedup vs baseline: 1.2956x; 1.2956x over previous
//
#include <hip/hip_runtime.h>
#include <hip/hip_bf16.h>
#include <math.h>

#define BB 2
#define SS 1024
#define DIM 2048
#define HH 16
#define QR 1536
#define KVR 512
#define DN 128
#define DR 64
#define DV 128
#define QKD 192
#define NT (BB*SS)

typedef __attribute__((ext_vector_type(8))) short bhalf8;
typedef __attribute__((ext_vector_type(4))) float f32x4;

__device__ __forceinline__ unsigned short f2b(float f) {
  union { float f; unsigned u; } v; v.f = f;
  unsigned r = v.u + 0x7fffu + ((v.u >> 16) & 1u);
  return (unsigned short)(r >> 16);
}
__device__ __forceinline__ float b2f(unsigned short h) {
  union { unsigned u; float f; } v; v.u = ((unsigned)h) << 16;
  return v.f;
}

__device__ __forceinline__ void gload16(const void* g, void* l) {
  __builtin_amdgcn_global_load_lds((const __attribute__((address_space(1))) void*)g,
                                   (__attribute__((address_space(3))) void*)l, 16, 0, 0);
}

// ---------------- plain f32 -> bf16 convert ----------------
__global__ void cvt_k(const float* __restrict__ in, unsigned short* __restrict__ out, long n4) {
  long i = (long)blockIdx.x * 256 + threadIdx.x;
  if (i >= n4) return;
  float4 v = ((const float4*)in)[i];
  ushort4 o; o.x = f2b(v.x); o.y = f2b(v.y); o.z = f2b(v.z); o.w = f2b(v.w);
  ((ushort4*)out)[i] = o;
}

// ---------------- fused conversions: xb, wqa, wkva, wkT ----------------
__global__ void cvtall_k(const float* __restrict__ x,     unsigned short* __restrict__ xb,
                         const float* __restrict__ wqa,   unsigned short* __restrict__ wqab,
                         const float* __restrict__ wkva,  unsigned short* __restrict__ wkvab,
                         const float* __restrict__ wk,    unsigned short* __restrict__ wkT)
{
  long i = (long)blockIdx.x * 256 + threadIdx.x;
  const float* in; unsigned short* out; long j;
  if (i < 1048576)      { in = x;    out = xb;    j = i; }
  else if (i < 1835008) { in = wqa;  out = wqab;  j = i - 1048576; }
  else if (i < 2129920) { in = wkva; out = wkvab; j = i - 1835008; }
  else {
    j = i - 2129920;
    if (j >= 262144) return;
    long e = j * 4;
    int d = (int)(e & 127), c = (int)((e >> 7) & 511), h = (int)(e >> 16);
    ushort4 o;
    o.x = f2b(wk[((long)h * 256 + d + 0) * 512 + c]);
    o.y = f2b(wk[((long)h * 256 + d + 1) * 512 + c]);
    o.z = f2b(wk[((long)h * 256 + d + 2) * 512 + c]);
    o.w = f2b(wk[((long)h * 256 + d + 3) * 512 + c]);
    ((ushort4*)wkT)[j] = o;
    return;
  }
  float4 v = ((const float4*)in)[j];
  ushort4 o; o.x = f2b(v.x); o.y = f2b(v.y); o.z = f2b(v.z); o.w = f2b(v.w);
  ((ushort4*)out)[j] = o;
}

// ---------------- fused post-flash conversions: wkb, wo ----------------
__global__ void cvt2_k(const float* __restrict__ wk, unsigned short* __restrict__ wkb,
                       const float* __restrict__ wo, unsigned short* __restrict__ wob)
{
  long i = (long)blockIdx.x * 256 + threadIdx.x;
  const float* in; unsigned short* out; long j;
  if (i < 524288) { in = wk; out = wkb; j = i; }
  else            { in = wo; out = wob; j = i - 524288; if (j >= 1048576) return; }
  float4 v = ((const float4*)in)[j];
  ushort4 o; o.x = f2b(v.x); o.y = f2b(v.y); o.z = f2b(v.z); o.w = f2b(v.w);
  ((ushort4*)out)[j] = o;
}

// V^T tile-major: kt[b][st(32)][vc][kv'] with kv' = kvl ^ (((vc>>1)&3)<<3)
__global__ void kcT_k(const unsigned short* __restrict__ kc, unsigned short* __restrict__ kt) {
  int idx = blockIdx.x * 256 + threadIdx.x;    // 2*512*1024
  int t = idx & 1023, c = (idx >> 10) & 511, b = idx >> 19;
  int csrc = c ^ ((t & 7) << 3);
  int kvd  = (t & 31) ^ (((c >> 1) & 3) << 3);
  kt[(((long)b * 32 + (t >> 5)) * 512 + c) * 32 + kvd] =
      kc[((long)b * SS + t) * 576 + csrc];
}

// ---------------- MFMA GEMM 128x128 (kept for q_abs) ----------------
template<int OBF>
__global__ __launch_bounds__(256) void gemm_mfma(
    const unsigned short* __restrict__ A, int lda, long sA,
    const unsigned short* __restrict__ B, int ldb, long sB,
    void* __restrict__ C, int ldc, long sC,
    int M, int N, int K, const float* __restrict__ bias)
{
  const int bx = blockIdx.x, by = blockIdx.y, bz = blockIdx.z;
  const int m0 = by * 128, n0 = bx * 128;
  A += (long)bz * sA;
  B += (long)bz * sB;

  __shared__ unsigned short As[4096];
  __shared__ unsigned short Bs[4096];
  const int tid = threadIdx.x, l = tid & 63, w = tid >> 6;
  const int wr = w >> 1, wc = w & 1;
  const int rA = l >> 2;
  const int c8 = (((l & 3) ^ ((l >> 2) & 3)) << 3);

  f32x4 acc[4][4] = {};

  const unsigned short* Ab0 = A + (long)(m0 + w * 16 + rA) * lda + c8;
  const unsigned short* Ab1 = Ab0 + (long)64 * lda;
  int nb0 = n0 + w * 16 + rA;      if (nb0 > N - 1) nb0 = N - 1;
  int nb1 = n0 + 64 + w * 16 + rA; if (nb1 > N - 1) nb1 = N - 1;
  const unsigned short* Bb0 = B + (long)nb0 * ldb + c8;
  const unsigned short* Bb1 = B + (long)nb1 * ldb + c8;

  const int ko = (((l >> 4) ^ (l & 3)) << 3);

  for (int k0 = 0; k0 < K; k0 += 32) {
    gload16(Ab0 + k0, &As[w * 512]);
    gload16(Ab1 + k0, &As[(w + 4) * 512]);
    gload16(Bb0 + k0, &Bs[w * 512]);
    gload16(Bb1 + k0, &Bs[(w + 4) * 512]);
    __syncthreads();
    bhalf8 af[4], bv[4];
#pragma unroll
    for (int m = 0; m < 4; ++m) {
      af[m] = *(const bhalf8*)&As[(wr * 64 + m * 16 + (l & 15)) * 32 + ko];
      bv[m] = *(const bhalf8*)&Bs[(wc * 64 + m * 16 + (l & 15)) * 32 + ko];
    }
#pragma unroll
    for (int m = 0; m < 4; ++m)
#pragma unroll
      for (int n = 0; n < 4; ++n)
        acc[m][n] = __builtin_amdgcn_mfma_f32_16x16x32_bf16(af[m], bv[n], acc[m][n], 0, 0, 0);
    __syncthreads();
  }

  const int ro = (l >> 4) << 2;
  const int co = l & 15;
#pragma unroll
  for (int m = 0; m < 4; ++m) {
    int row = m0 + wr * 64 + m * 16 + ro;
#pragma unroll
    for (int n = 0; n < 4; ++n) {
      int col = n0 + wc * 64 + n * 16 + co;
      if (col < N) {
        float bvl = bias ? bias[col] : 0.f;
#pragma unroll
        for (int r = 0; r < 4; ++r) {
          float v = acc[m][n][r] + bvl;
          long off = (long)bz * sC + (long)(row + r) * ldc + col;
          if (OBF) ((unsigned short*)C)[off] = f2b(v);
          else     ((float*)C)[off] = v;
        }
      }
    }
  }
}

// ---------------- MFMA GEMM 64x128 tile (high-occupancy variant) ----------------
// XSWZ=1: launched 1D (grid = nbx*nby, %8==0); XCD-chunked column-major decode so
// blocks sharing a B-panel co-reside on one XCD's L2.
template<int OBF, int ROPE, int SPLIT, int XSWZ>
__global__ __launch_bounds__(256) void gemm64(
    const unsigned short* __restrict__ A, int lda, long sA,
    const unsigned short* __restrict__ B, int ldb, long sB,
    void* __restrict__ C, int ldc, long sC,
    int M, int N, int K, const float* __restrict__ bias,
    unsigned short* __restrict__ qcat, const float* __restrict__ cosT,
    const float* __restrict__ sinT,
    float* __restrict__ C2, const float* __restrict__ bias2)
{
  int bx, by;
  const int bz = blockIdx.z;
  if (XSWZ) {
    int nby = M >> 6;
    int idx = (blockIdx.x & 7) * (gridDim.x >> 3) + (blockIdx.x >> 3);
    bx = idx / nby;
    by = idx - bx * nby;
  } else {
    bx = blockIdx.x; by = blockIdx.y;
  }
  const int m0 = by * 64, n0 = bx * 128;
  A += (long)bz * sA;
  B += (long)bz * sB;

  __shared__ unsigned short As[2048];
  __shared__ unsigned short Bs[4096];
  const int tid = threadIdx.x, l = tid & 63, w = tid >> 6;
  const int rA = l >> 2;
  const int c8 = (((l & 3) ^ ((l >> 2) & 3)) << 3);

  f32x4 acc[8] = {};

  const unsigned short* Ab0 = A + (long)(m0 + w * 16 + rA) * lda + c8;
  int nb0 = n0 + w * 16 + rA;      if (nb0 > N - 1) nb0 = N - 1;
  int nb1 = n0 + 64 + w * 16 + rA; if (nb1 > N - 1) nb1 = N - 1;
  const unsigned short* Bb0 = B + (long)nb0 * ldb + c8;
  const unsigned short* Bb1 = B + (long)nb1 * ldb + c8;

  const int ko = (((l >> 4) ^ (l & 3)) << 3);

  for (int k0 = 0; k0 < K; k0 += 32) {
    gload16(Ab0 + k0, &As[w * 512]);
    gload16(Bb0 + k0, &Bs[w * 512]);
    gload16(Bb1 + k0, &Bs[(w + 4) * 512]);
    __syncthreads();
    bhalf8 af = *(const bhalf8*)&As[(w * 16 + (l & 15)) * 32 + ko];
    bhalf8 bv[8];
#pragma unroll
    for (int n = 0; n < 8; ++n)
      bv[n] = *(const bhalf8*)&Bs[(n * 16 + (l & 15)) * 32 + ko];
#pragma unroll
    for (int n = 0; n < 8; ++n)
      acc[n] = __builtin_amdgcn_mfma_f32_16x16x32_bf16(af, bv[n], acc[n], 0, 0, 0);
    __syncthreads();
  }

  const int ro = (l >> 4) << 2;
  const int co = l & 15;
#pragma unroll
  for (int r = 0; r < 4; ++r) {
    int row = m0 + w * 16 + ro + r;
    float v[8];
#pragma unroll
    for (int n = 0; n < 8; ++n) {
      int col = n0 + n * 16 + co;
      float bv2 = 0.f;
      if (SPLIT) bv2 = (col < QR) ? bias[col] : ((col < QR + 576) ? bias2[col - QR] : 0.f);
      else if (bias && col < N) bv2 = bias[col];
      v[n] = acc[n][r] + bv2;
    }
    if (ROPE) {
      int s = row & (SS - 1);
#pragma unroll
      for (int n = 0; n < 8; ++n) {
        int col0 = n0 + n * 16;
        int cm0 = col0 % 192;
        if (cm0 < 128) {
          ((unsigned short*)C)[(long)row * ldc + col0 + co] = f2b(v[n]);
        } else if (cm0 == 128 || cm0 == 144) {
          int d = cm0 - 128 + co;
          float cl = cosT[s * DR + d],      sl = sinT[s * DR + d];
          float ch = cosT[s * DR + d + 32], sh = sinT[s * DR + d + 32];
          float o_lo = v[n] * cl - v[n + 2] * sl;
          float o_hi = v[n + 2] * ch + v[n] * sh;
          unsigned short* qp = qcat + ((long)(col0 / 192) * NT + row) * 576 + 512;
          qp[d]      = f2b(o_lo);
          qp[d + 32] = f2b(o_hi);
        }
      }
    } else if (SPLIT) {
#pragma unroll
      for (int n = 0; n < 8; ++n) {
        int col = n0 + n * 16 + co;
        if (col < QR)            ((float*)C)[(long)row * ldc + col] = v[n];
        else if (col < QR + 576) C2[(long)row * 576 + (col - QR)] = v[n];
      }
    } else {
#pragma unroll
      for (int n = 0; n < 8; ++n) {
        int col = n0 + n * 16 + co;
        if (col < N) {
          long off = (long)bz * sC + (long)row * ldc + col;
          if (OBF) ((unsigned short*)C)[off] = f2b(v[n]);
          else     ((float*)C)[off] = v[n];
        }
      }
    }
  }
}

// ---------------- RMSNorm fp32 -> bf16 (optional col swizzle by row) ----------------
template<int SWZ>
__global__ void rmsnorm_k(const float* __restrict__ in, int ldin,
                          unsigned short* __restrict__ out, int ldout,
                          const float* __restrict__ w, int N) {
  long row = blockIdx.x;
  const float* x = in + row * ldin;
  unsigned short* y = out + row * ldout;
  float ss = 0.f;
  for (int i = threadIdx.x; i < N; i += 256) { float u = x[i]; ss += u * u; }
  for (int o = 32; o > 0; o >>= 1) ss += __shfl_down(ss, o);
  __shared__ float red[4];
  int lane = threadIdx.x & 63, wid = threadIdx.x >> 6;
  if (lane == 0) red[wid] = ss;
  __syncthreads();
  float r = rsqrtf((red[0] + red[1] + red[2] + red[3]) / (float)N + 1e-6f);
  int sw = SWZ ? (((int)row & 7) << 3) : 0;
  for (int i = threadIdx.x; i < N; i += 256) y[i ^ sw] = f2b(x[i] * r * w[i]);
}

// ---------------- RoPE on k_pe -> kcatb cols 512..575 (swizzled) ----------------
__global__ void rope_k_k(const float* __restrict__ kv, unsigned short* __restrict__ kc,
                         const float* __restrict__ cosT, const float* __restrict__ sinT) {
  int idx = blockIdx.x * 256 + threadIdx.x;
  int d = idx & 31, t = idx >> 5, s = t & (SS - 1);
  const float* p = kv + (long)t * 576 + 512;
  float x1 = p[d], x2 = p[d + 32];
  float c1 = cosT[s * DR + d],      s1 = sinT[s * DR + d];
  float c2 = cosT[s * DR + 32 + d], s2 = sinT[s * DR + 32 + d];
  unsigned short* o = kc + (long)t * 576;
  int sw = (t & 7) << 3;
  o[(512 + d) ^ sw]      = f2b(x1 * c1 - x2 * s1);
  o[(512 + d + 32) ^ sw] = f2b(x2 * c2 + x1 * s2);
}

// ---------------- fused flash attention v5 (r13-proven): staged K+V, defer-max ----------------
__global__ __launch_bounds__(256) void flash_k(
    const unsigned short* __restrict__ qcat,   // [16][NT][576] linear
    const unsigned short* __restrict__ kcb,    // [B][S][576]  col-swizzled ^((t&7)<<3)
    const unsigned short* __restrict__ kct,    // [B][32][512][32] tile-major, swizzled
    unsigned short* __restrict__ omid)         // [16][NT][512]
{
  __shared__ __align__(16) char lds[73728];
  char* Kl = lds;                // 36,864 B
  char* Vl = lds + 36864;        // 32,768 B
  char* Pl = lds + 69632;        //  4,096 B

  const int bid = blockIdx.x;
  const int qt = 15 - (bid >> 5);
  const int bh = bid & 31;
  const int b = bh & 1, h = bh >> 1;
  const int tid = threadIdx.x, l = tid & 63, w = tid >> 6;
  const int lo = l & 15, hi = l >> 4;

  const unsigned short* qrow =
      qcat + ((long)h * NT + b * SS + qt * 64 + w * 16 + lo) * 576 + hi * 8;
  bhalf8 qf[18];
#pragma unroll
  for (int ks = 0; ks < 18; ++ks) qf[ks] = *(const bhalf8*)(qrow + ks * 32);

  f32x4 po[32] = {};                  // O[q=hi*4+r][vc=nv*16+lo]
  float mrow[4] = {-1e30f, -1e30f, -1e30f, -1e30f};
  float lrow[4] = {0.f, 0.f, 0.f, 0.f};
  const float sc = 0.07216878364870323f;   // 1/sqrt(192)
  char* Pwv = Pl + w * 1024;

  const char* ksrc = (const char*)kcb + (long)b * SS * 1152;
  const char* vsrc = (const char*)kct + (long)b * 32 * 32768;
  const int smax = 2 * qt + 1;

  for (int st = 0; st <= smax; ++st) {
#pragma unroll
    for (int i = 0; i < 9; ++i) {
      int off = (w + i * 4) * 1024 + l * 16;
      gload16(ksrc + off, Kl + off);
    }
#pragma unroll
    for (int i = 0; i < 8; ++i) {
      int off = (w + i * 4) * 1024 + l * 16;
      gload16(vsrc + off, Vl + off);
    }
    __syncthreads();

    // QK^T
    f32x4 sa[2] = {};
    __builtin_amdgcn_s_setprio(1);
#pragma unroll
    for (int ks = 0; ks < 18; ++ks) {
#pragma unroll
      for (int n = 0; n < 2; ++n) {
        int kv = n * 16 + lo;
        bhalf8 kf = *(const bhalf8*)(Kl + kv * 1152 + (((ks * 4 + hi) ^ (kv & 7)) << 4));
        sa[n] = __builtin_amdgcn_mfma_f32_16x16x32_bf16(qf[ks], kf, sa[n], 0, 0, 0);
      }
    }
    __builtin_amdgcn_s_setprio(0);
    // scale + causal mask
    if (st >= 2 * qt) {
      const int kv0 = st * 32;
#pragma unroll
      for (int n = 0; n < 2; ++n) {
        int kvg = kv0 + n * 16 + lo;
#pragma unroll
        for (int r = 0; r < 4; ++r) {
          int qg = qt * 64 + w * 16 + hi * 4 + r;
          sa[n][r] = (kvg > qg) ? -1e30f : sa[n][r] * sc;
        }
      }
    } else {
#pragma unroll
      for (int n = 0; n < 2; ++n)
#pragma unroll
        for (int r = 0; r < 4; ++r) sa[n][r] *= sc;
    }
    // row max
    float pmax[4];
#pragma unroll
    for (int r = 0; r < 4; ++r) {
      float v = fmaxf(sa[0][r], sa[1][r]);
      v = fmaxf(v, __shfl_xor(v, 1));
      v = fmaxf(v, __shfl_xor(v, 2));
      v = fmaxf(v, __shfl_xor(v, 4));
      v = fmaxf(v, __shfl_xor(v, 8));
      pmax[r] = v;
    }
    // defer-max rescale (THR=8)
    bool need = false;
#pragma unroll
    for (int r = 0; r < 4; ++r) need |= (pmax[r] > mrow[r] + 8.f);
    if (__any(need)) {
#pragma unroll
      for (int r = 0; r < 4; ++r) {
        float mn = fmaxf(mrow[r], pmax[r]);
        float fac = __expf(mrow[r] - mn);
        mrow[r] = mn;
        lrow[r] *= fac;
#pragma unroll
        for (int nv = 0; nv < 32; ++nv) po[nv][r] *= fac;
      }
    }
    // P = exp(S - m), row sums
    float rs[4] = {0.f, 0.f, 0.f, 0.f};
#pragma unroll
    for (int n = 0; n < 2; ++n)
#pragma unroll
      for (int r = 0; r < 4; ++r) {
        float p = __expf(sa[n][r] - mrow[r]);
        sa[n][r] = p;
        rs[r] += p;
      }
#pragma unroll
    for (int r = 0; r < 4; ++r) {
      float v = rs[r];
      v += __shfl_xor(v, 1); v += __shfl_xor(v, 2);
      v += __shfl_xor(v, 4); v += __shfl_xor(v, 8);
      lrow[r] += v;
    }
    // P -> bf16 -> wave-private LDS
#pragma unroll
    for (int n = 0; n < 2; ++n)
#pragma unroll
      for (int r = 0; r < 4; ++r) {
        int q = hi * 4 + r, kv = n * 16 + lo;
        *(unsigned short*)(Pwv + q * 64 + ((kv * 2) ^ ((q & 3) << 4))) = f2b(sa[n][r]);
      }
    // PV
    bhalf8 pa = *(const bhalf8*)(Pwv + lo * 64 + ((hi * 16) ^ ((lo & 3) << 4)));
    __builtin_amdgcn_s_setprio(1);
#pragma unroll
    for (int nv = 0; nv < 32; ++nv) {
      int vc = nv * 16 + lo;
      bhalf8 vb = *(const bhalf8*)(Vl + vc * 64 + ((hi ^ ((vc >> 1) & 3)) << 4));
      po[nv] = __builtin_amdgcn_mfma_f32_16x16x32_bf16(pa, vb, po[nv], 0, 0, 0);
    }
    __builtin_amdgcn_s_setprio(0);
    __syncthreads();
    ksrc += 36864; vsrc += 32768;
  }

  // epilogue
  unsigned short* orow = omid + ((long)h * NT + b * SS + qt * 64) * 512;
  float inv[4];
#pragma unroll
  for (int r = 0; r < 4; ++r) inv[r] = 1.f / lrow[r];
#pragma unroll
  for (int nv = 0; nv < 32; ++nv)
#pragma unroll
    for (int r = 0; r < 4; ++r) {
      int q = w * 16 + hi * 4 + r;
      orow[(long)q * 512 + nv * 16 + lo] = f2b(po[nv][r] * inv[r]);
    }
}

// ---------------- launch ----------------
extern "C" void kernel_launch(void* const* d_in, const int* in_sizes, int n_in,
                              void* d_out, int out_size, void* d_ws, size_t ws_size,
                              hipStream_t stream) {
  const float* x        = (const float*)d_in[0];
  const float* wq_a_w   = (const float*)d_in[2];
  const float* wq_a_b   = (const float*)d_in[3];
  const float* q_norm_w = (const float*)d_in[4];
  const float* wq_b_w   = (const float*)d_in[5];
  const float* wq_b_b   = (const float*)d_in[6];
  const float* wkv_a_w  = (const float*)d_in[7];
  const float* wkv_a_b  = (const float*)d_in[8];
  const float* kv_norm_w= (const float*)d_in[9];
  const float* wk_b_w   = (const float*)d_in[10];
  const float* wo_w     = (const float*)d_in[11];
  const float* wo_bias  = (const float*)d_in[12];
  const float* cosT     = (const float*)d_in[13];
  const float* sinT     = (const float*)d_in[14];
  float* out = (float*)d_out;

  char* W = (char*)d_ws;
  // core live-through-flash buffers
  unsigned short* kcatb  = (unsigned short*)(W + 0);          // 2.36 MB [B*S][576] swz
  unsigned short* kcatT  = (unsigned short*)(W + 2359296);    // 2.10 MB [B][32][512][32] swz
  unsigned short* qcat   = (unsigned short*)(W + 4456448);    // 37.75 MB [16][NT][576]
  unsigned short* o_mid  = (unsigned short*)(W + 42205184);   // 33.55 MB [16][NT][512]
  // pre-flash aliases in qcat region — ALL dead before q_b writes qcat pe cols:
  unsigned short* xb     = (unsigned short*)(W + 4456448);    // 8.39 MB (dead after qkv_a)
  unsigned short* wqa_b  = (unsigned short*)(W + 12845056);   // 6.29 MB } contiguous: combined
  unsigned short* wkva_b = (unsigned short*)(W + 19136512);   // 2.36 MB } B of 2112 rows
  float*          kv_f32 = (float*)        (W + 21495808);    // 4.72 MB (dead after rope_k)
  // pre-flash aliases in o_mid region (dead before flash writes o_mid)
  unsigned short* qb     = (unsigned short*)(W + 42205184);   // 12.58 MB [NT][3072]
  unsigned short* wkT_b  = (unsigned short*)(W + 54788096);   // 2.10 MB
  float*          qn_f32 = (float*)        (W + 56885248);    // 12.58 MB
  unsigned short* wqb_b  = (unsigned short*)(W + 56885248);   // 9.44 MB (overlays qn after rmsnorm_q)
  unsigned short* qnb    = (unsigned short*)(W + 69468160);   // 6.29 MB (end 75,759,616)
  // post-flash aliases in qcat region (qcat dead after flash)
  unsigned short* wkb_b  = (unsigned short*)(W + 4456448);    // 4.19 MB
  unsigned short* ohead  = (unsigned short*)(W + 8650752);    // 8.39 MB [NT][2048]
  unsigned short* wo_b16 = (unsigned short*)(W + 17039360);   // 8.39 MB

  // fused conversions (xb, wqa, wkva, wkT); wqb converted later into dead qn slot
  cvtall_k<<<9344, 256, 0, stream>>>(x, xb, wq_a_w, wqa_b, wkv_a_w, wkva_b, wk_b_w, wkT_b);

  // combined q_a + kv_a: [qn | kv] = x @ [wqa; wkva]^T  (N=2112, split epilogue, XCD swz)
  gemm64<0,0,1,1><<<dim3(544, 1, 1), 256, 0, stream>>>(
      xb, DIM, 0, wqa_b, DIM, 0, qn_f32, QR, 0, NT, QR + 576, DIM, wq_a_b,
      nullptr, nullptr, nullptr, kv_f32, wkv_a_b);

  // kv chain (kills xb / wkva / kv_f32 before q_b touches qcat)
  rmsnorm_k<1><<<NT, 256, 0, stream>>>(kv_f32, 576, kcatb, 576, kv_norm_w, KVR);
  rope_k_k<<<256, 256, 0, stream>>>(kv_f32, kcatb, cosT, sinT);
  kcT_k<<<4096, 256, 0, stream>>>(kcatb, kcatT);

  // q path
  rmsnorm_k<0><<<NT, 256, 0, stream>>>(qn_f32, QR, qnb, QR, q_norm_w, QR);
  cvt_k<<<4608, 256, 0, stream>>>(wq_b_w, wqb_b, (long)3072 * QR / 4);   // into dead qn slot
  // q_b: qb = qnb @ wq_b^T (bf16); pe windows rope'd into qcat cols 512..575 (XCD swz)
  gemm64<1,1,0,1><<<dim3(768, 1, 1), 256, 0, stream>>>(
      qnb, QR, 0, wqb_b, QR, 0, qb, 3072, 0, NT, 3072, QR, wq_b_b,
      qcat, cosT, sinT, nullptr, nullptr);

  // q_abs for all 16 heads: qcat[z][:, :512] = q_nope_z @ wkT[z]^T  (128x128 path)
  gemm_mfma<1><<<dim3(4, NT/128, 16), 256, 0, stream>>>(
      qb, 3072, QKD, wkT_b, DN, (long)KVR * DN,
      qcat, 576, (long)NT * 576, NT, KVR, DN, nullptr);

  // fused attention, all heads, one dispatch (flat-descending qt, dispatch backfill)
  flash_k<<<512, 256, 0, stream>>>(qcat, kcatb, kcatT, o_mid);

  // post-flash conversions (wkb, wo) in one kernel  [qcat dead]
  cvt2_k<<<6144, 256, 0, stream>>>(wk_b_w, wkb_b, wo_w, wo_b16);

  // V-absorb: ohead[:, z*128..] = o_mid[z] @ wkv_b_v[z]^T  (64x128 tiles, z-grid)
  gemm64<1,0,0,0><<<dim3(1, NT/64, 16), 256, 0, stream>>>(
      o_mid, KVR, (long)NT * KVR,
      wkb_b + (long)DN * KVR, KVR, (long)256 * KVR,
      ohead, HH * DV, DV, NT, DV, KVR, nullptr,
      nullptr, nullptr, nullptr, nullptr, nullptr);

  // out = o_head @ wo^T + b (fp32, XCD swz)
  gemm64<0,0,0,1><<<dim3(512, 1, 1), 256, 0, stream>>>(
      ohead, 2048, 0, wo_b16, 2048, 0, out, DIM, 0, NT, DIM, 2048, wo_bias,
      nullptr, nullptr, nullptr, nullptr, nullptr);
}

// Round 16
// 330.938 us; speedup vs baseline: 1.3030x; 1.0057x over previous
//
#include <hip/hip_runtime.h>
#include <hip/hip_bf16.h>
#include <math.h>

#define BB 2
#define SS 1024
#define DIM 2048
#define HH 16
#define QR 1536
#define KVR 512
#define DN 128
#define DR 64
#define DV 128
#define QKD 192
#define NT (BB*SS)

typedef __attribute__((ext_vector_type(8))) short bhalf8;
typedef __attribute__((ext_vector_type(4))) float f32x4;

__device__ __forceinline__ unsigned short f2b(float f) {
  union { float f; unsigned u; } v; v.f = f;
  unsigned r = v.u + 0x7fffu + ((v.u >> 16) & 1u);
  return (unsigned short)(r >> 16);
}
__device__ __forceinline__ float b2f(unsigned short h) {
  union { unsigned u; float f; } v; v.u = ((unsigned)h) << 16;
  return v.f;
}

__device__ __forceinline__ void gload16(const void* g, void* l) {
  __builtin_amdgcn_global_load_lds((const __attribute__((address_space(1))) void*)g,
                                   (__attribute__((address_space(3))) void*)l, 16, 0, 0);
}

// ---------------- plain f32 -> bf16 convert ----------------
__global__ void cvt_k(const float* __restrict__ in, unsigned short* __restrict__ out, long n4) {
  long i = (long)blockIdx.x * 256 + threadIdx.x;
  if (i >= n4) return;
  float4 v = ((const float4*)in)[i];
  ushort4 o; o.x = f2b(v.x); o.y = f2b(v.y); o.z = f2b(v.z); o.w = f2b(v.w);
  ((ushort4*)out)[i] = o;
}

// ---------------- fused conversions: xb, wqa, wkva, wkT ----------------
__global__ void cvtall_k(const float* __restrict__ x,     unsigned short* __restrict__ xb,
                         const float* __restrict__ wqa,   unsigned short* __restrict__ wqab,
                         const float* __restrict__ wkva,  unsigned short* __restrict__ wkvab,
                         const float* __restrict__ wk,    unsigned short* __restrict__ wkT)
{
  long i = (long)blockIdx.x * 256 + threadIdx.x;
  const float* in; unsigned short* out; long j;
  if (i < 1048576)      { in = x;    out = xb;    j = i; }
  else if (i < 1835008) { in = wqa;  out = wqab;  j = i - 1048576; }
  else if (i < 2129920) { in = wkva; out = wkvab; j = i - 1835008; }
  else {
    j = i - 2129920;
    if (j >= 262144) return;
    long e = j * 4;
    int d = (int)(e & 127), c = (int)((e >> 7) & 511), h = (int)(e >> 16);
    ushort4 o;
    o.x = f2b(wk[((long)h * 256 + d + 0) * 512 + c]);
    o.y = f2b(wk[((long)h * 256 + d + 1) * 512 + c]);
    o.z = f2b(wk[((long)h * 256 + d + 2) * 512 + c]);
    o.w = f2b(wk[((long)h * 256 + d + 3) * 512 + c]);
    ((ushort4*)wkT)[j] = o;
    return;
  }
  float4 v = ((const float4*)in)[j];
  ushort4 o; o.x = f2b(v.x); o.y = f2b(v.y); o.z = f2b(v.z); o.w = f2b(v.w);
  ((ushort4*)out)[j] = o;
}

// ---------------- fused post-flash conversions: wkb, wo ----------------
__global__ void cvt2_k(const float* __restrict__ wk, unsigned short* __restrict__ wkb,
                       const float* __restrict__ wo, unsigned short* __restrict__ wob)
{
  long i = (long)blockIdx.x * 256 + threadIdx.x;
  const float* in; unsigned short* out; long j;
  if (i < 524288) { in = wk; out = wkb; j = i; }
  else            { in = wo; out = wob; j = i - 524288; if (j >= 1048576) return; }
  float4 v = ((const float4*)in)[j];
  ushort4 o; o.x = f2b(v.x); o.y = f2b(v.y); o.z = f2b(v.z); o.w = f2b(v.w);
  ((ushort4*)out)[j] = o;
}

// V^T tile-major: kt[b][st(32)][vc][kv'] with kv' = kvl ^ (((vc>>1)&3)<<3)
__global__ void kcT_k(const unsigned short* __restrict__ kc, unsigned short* __restrict__ kt) {
  int idx = blockIdx.x * 256 + threadIdx.x;    // 2*512*1024
  int t = idx & 1023, c = (idx >> 10) & 511, b = idx >> 19;
  int csrc = c ^ ((t & 7) << 3);
  int kvd  = (t & 31) ^ (((c >> 1) & 3) << 3);
  kt[(((long)b * 32 + (t >> 5)) * 512 + c) * 32 + kvd] =
      kc[((long)b * SS + t) * 576 + csrc];
}

// ---------------- MFMA GEMM 128x128 (kept for q_abs) ----------------
template<int OBF>
__global__ __launch_bounds__(256) void gemm_mfma(
    const unsigned short* __restrict__ A, int lda, long sA,
    const unsigned short* __restrict__ B, int ldb, long sB,
    void* __restrict__ C, int ldc, long sC,
    int M, int N, int K, const float* __restrict__ bias)
{
  const int bx = blockIdx.x, by = blockIdx.y, bz = blockIdx.z;
  const int m0 = by * 128, n0 = bx * 128;
  A += (long)bz * sA;
  B += (long)bz * sB;

  __shared__ unsigned short As[4096];
  __shared__ unsigned short Bs[4096];
  const int tid = threadIdx.x, l = tid & 63, w = tid >> 6;
  const int wr = w >> 1, wc = w & 1;
  const int rA = l >> 2;
  const int c8 = (((l & 3) ^ ((l >> 2) & 3)) << 3);

  f32x4 acc[4][4] = {};

  const unsigned short* Ab0 = A + (long)(m0 + w * 16 + rA) * lda + c8;
  const unsigned short* Ab1 = Ab0 + (long)64 * lda;
  int nb0 = n0 + w * 16 + rA;      if (nb0 > N - 1) nb0 = N - 1;
  int nb1 = n0 + 64 + w * 16 + rA; if (nb1 > N - 1) nb1 = N - 1;
  const unsigned short* Bb0 = B + (long)nb0 * ldb + c8;
  const unsigned short* Bb1 = B + (long)nb1 * ldb + c8;

  const int ko = (((l >> 4) ^ (l & 3)) << 3);

  for (int k0 = 0; k0 < K; k0 += 32) {
    gload16(Ab0 + k0, &As[w * 512]);
    gload16(Ab1 + k0, &As[(w + 4) * 512]);
    gload16(Bb0 + k0, &Bs[w * 512]);
    gload16(Bb1 + k0, &Bs[(w + 4) * 512]);
    __syncthreads();
    bhalf8 af[4], bv[4];
#pragma unroll
    for (int m = 0; m < 4; ++m) {
      af[m] = *(const bhalf8*)&As[(wr * 64 + m * 16 + (l & 15)) * 32 + ko];
      bv[m] = *(const bhalf8*)&Bs[(wc * 64 + m * 16 + (l & 15)) * 32 + ko];
    }
#pragma unroll
    for (int m = 0; m < 4; ++m)
#pragma unroll
      for (int n = 0; n < 4; ++n)
        acc[m][n] = __builtin_amdgcn_mfma_f32_16x16x32_bf16(af[m], bv[n], acc[m][n], 0, 0, 0);
    __syncthreads();
  }

  const int ro = (l >> 4) << 2;
  const int co = l & 15;
#pragma unroll
  for (int m = 0; m < 4; ++m) {
    int row = m0 + wr * 64 + m * 16 + ro;
#pragma unroll
    for (int n = 0; n < 4; ++n) {
      int col = n0 + wc * 64 + n * 16 + co;
      if (col < N) {
        float bvl = bias ? bias[col] : 0.f;
#pragma unroll
        for (int r = 0; r < 4; ++r) {
          float v = acc[m][n][r] + bvl;
          long off = (long)bz * sC + (long)(row + r) * ldc + col;
          if (OBF) ((unsigned short*)C)[off] = f2b(v);
          else     ((float*)C)[off] = v;
        }
      }
    }
  }
}

// ---------------- MFMA GEMM 64x128 tile (high-occupancy variant) ----------------
// XSWZ=1: 1D grid, XCD-chunked decode.  SPLIT=1: bf16 outputs qn (ld QR) / kv (ld 576).
template<int OBF, int ROPE, int SPLIT, int XSWZ>
__global__ __launch_bounds__(256) void gemm64(
    const unsigned short* __restrict__ A, int lda, long sA,
    const unsigned short* __restrict__ B, int ldb, long sB,
    void* __restrict__ C, int ldc, long sC,
    int M, int N, int K, const float* __restrict__ bias,
    unsigned short* __restrict__ qcat, const float* __restrict__ cosT,
    const float* __restrict__ sinT,
    unsigned short* __restrict__ C2, const float* __restrict__ bias2)
{
  int bx, by;
  const int bz = blockIdx.z;
  if (XSWZ) {
    int nby = M >> 6;
    int idx = (blockIdx.x & 7) * (gridDim.x >> 3) + (blockIdx.x >> 3);
    bx = idx / nby;
    by = idx - bx * nby;
  } else {
    bx = blockIdx.x; by = blockIdx.y;
  }
  const int m0 = by * 64, n0 = bx * 128;
  A += (long)bz * sA;
  B += (long)bz * sB;

  __shared__ unsigned short As[2048];
  __shared__ unsigned short Bs[4096];
  const int tid = threadIdx.x, l = tid & 63, w = tid >> 6;
  const int rA = l >> 2;
  const int c8 = (((l & 3) ^ ((l >> 2) & 3)) << 3);

  f32x4 acc[8] = {};

  const unsigned short* Ab0 = A + (long)(m0 + w * 16 + rA) * lda + c8;
  int nb0 = n0 + w * 16 + rA;      if (nb0 > N - 1) nb0 = N - 1;
  int nb1 = n0 + 64 + w * 16 + rA; if (nb1 > N - 1) nb1 = N - 1;
  const unsigned short* Bb0 = B + (long)nb0 * ldb + c8;
  const unsigned short* Bb1 = B + (long)nb1 * ldb + c8;

  const int ko = (((l >> 4) ^ (l & 3)) << 3);

  for (int k0 = 0; k0 < K; k0 += 32) {
    gload16(Ab0 + k0, &As[w * 512]);
    gload16(Bb0 + k0, &Bs[w * 512]);
    gload16(Bb1 + k0, &Bs[(w + 4) * 512]);
    __syncthreads();
    bhalf8 af = *(const bhalf8*)&As[(w * 16 + (l & 15)) * 32 + ko];
    bhalf8 bv[8];
#pragma unroll
    for (int n = 0; n < 8; ++n)
      bv[n] = *(const bhalf8*)&Bs[(n * 16 + (l & 15)) * 32 + ko];
#pragma unroll
    for (int n = 0; n < 8; ++n)
      acc[n] = __builtin_amdgcn_mfma_f32_16x16x32_bf16(af, bv[n], acc[n], 0, 0, 0);
    __syncthreads();
  }

  const int ro = (l >> 4) << 2;
  const int co = l & 15;
#pragma unroll
  for (int r = 0; r < 4; ++r) {
    int row = m0 + w * 16 + ro + r;
    float v[8];
#pragma unroll
    for (int n = 0; n < 8; ++n) {
      int col = n0 + n * 16 + co;
      float bv2 = 0.f;
      if (SPLIT) bv2 = (col < QR) ? bias[col] : ((col < QR + 576) ? bias2[col - QR] : 0.f);
      else if (bias && col < N) bv2 = bias[col];
      v[n] = acc[n][r] + bv2;
    }
    if (ROPE) {
      int s = row & (SS - 1);
#pragma unroll
      for (int n = 0; n < 8; ++n) {
        int col0 = n0 + n * 16;
        int cm0 = col0 % 192;
        if (cm0 < 128) {
          ((unsigned short*)C)[(long)row * ldc + col0 + co] = f2b(v[n]);
        } else if (cm0 == 128 || cm0 == 144) {
          int d = cm0 - 128 + co;
          float cl = cosT[s * DR + d],      sl = sinT[s * DR + d];
          float ch = cosT[s * DR + d + 32], sh = sinT[s * DR + d + 32];
          float o_lo = v[n] * cl - v[n + 2] * sl;
          float o_hi = v[n + 2] * ch + v[n] * sh;
          unsigned short* qp = qcat + ((long)(col0 / 192) * NT + row) * 576 + 512;
          qp[d]      = f2b(o_lo);
          qp[d + 32] = f2b(o_hi);
        }
      }
    } else if (SPLIT) {
#pragma unroll
      for (int n = 0; n < 8; ++n) {
        int col = n0 + n * 16 + co;
        if (col < QR)            ((unsigned short*)C)[(long)row * ldc + col] = f2b(v[n]);
        else if (col < QR + 576) C2[(long)row * 576 + (col - QR)] = f2b(v[n]);
      }
    } else {
#pragma unroll
      for (int n = 0; n < 8; ++n) {
        int col = n0 + n * 16 + co;
        if (col < N) {
          long off = (long)bz * sC + (long)row * ldc + col;
          if (OBF) ((unsigned short*)C)[off] = f2b(v[n]);
          else     ((float*)C)[off] = v[n];
        }
      }
    }
  }
}

// ---------------- RMSNorm bf16 -> bf16 ----------------
// ROPEK=1: additionally rope cols 512..575 (bf16 in) -> out swizzled pe cols.
template<int SWZ, int ROPEK>
__global__ void rmsnorm_k(const unsigned short* __restrict__ in, int ldin,
                          unsigned short* __restrict__ out, int ldout,
                          const float* __restrict__ w, int N,
                          const float* __restrict__ cosT, const float* __restrict__ sinT) {
  long row = blockIdx.x;
  const unsigned short* x = in + row * ldin;
  unsigned short* y = out + row * ldout;
  float ss = 0.f;
  for (int i = threadIdx.x; i < N; i += 256) { float u = b2f(x[i]); ss += u * u; }
  for (int o = 32; o > 0; o >>= 1) ss += __shfl_down(ss, o);
  __shared__ float red[4];
  int lane = threadIdx.x & 63, wid = threadIdx.x >> 6;
  if (lane == 0) red[wid] = ss;
  __syncthreads();
  float r = rsqrtf((red[0] + red[1] + red[2] + red[3]) / (float)N + 1e-6f);
  int sw = SWZ ? (((int)row & 7) << 3) : 0;
  for (int i = threadIdx.x; i < N; i += 256) y[i ^ sw] = f2b(b2f(x[i]) * r * w[i]);
  if (ROPEK && threadIdx.x < 32) {
    int d = threadIdx.x;
    int s = (int)(row & (SS - 1));
    float x1 = b2f(x[512 + d]), x2 = b2f(x[512 + d + 32]);
    float c1 = cosT[s * DR + d],      s1 = sinT[s * DR + d];
    float c2 = cosT[s * DR + 32 + d], s2 = sinT[s * DR + 32 + d];
    y[(512 + d) ^ sw]      = f2b(x1 * c1 - x2 * s1);
    y[(512 + d + 32) ^ sw] = f2b(x2 * c2 + x1 * s2);
  }
}

// ---------------- fused flash attention v5 (proven): staged K+V, defer-max ----------------
__global__ __launch_bounds__(256) void flash_k(
    const unsigned short* __restrict__ qcat,   // [16][NT][576] linear
    const unsigned short* __restrict__ kcb,    // [B][S][576]  col-swizzled ^((t&7)<<3)
    const unsigned short* __restrict__ kct,    // [B][32][512][32] tile-major, swizzled
    unsigned short* __restrict__ omid)         // [16][NT][512]
{
  __shared__ __align__(16) char lds[73728];
  char* Kl = lds;                // 36,864 B
  char* Vl = lds + 36864;        // 32,768 B
  char* Pl = lds + 69632;        //  4,096 B

  const int bid = blockIdx.x;
  const int qt = 15 - (bid >> 5);
  const int bh = bid & 31;
  const int b = bh & 1, h = bh >> 1;
  const int tid = threadIdx.x, l = tid & 63, w = tid >> 6;
  const int lo = l & 15, hi = l >> 4;

  const unsigned short* qrow =
      qcat + ((long)h * NT + b * SS + qt * 64 + w * 16 + lo) * 576 + hi * 8;
  bhalf8 qf[18];
#pragma unroll
  for (int ks = 0; ks < 18; ++ks) qf[ks] = *(const bhalf8*)(qrow + ks * 32);

  f32x4 po[32] = {};                  // O[q=hi*4+r][vc=nv*16+lo]
  float mrow[4] = {-1e30f, -1e30f, -1e30f, -1e30f};
  float lrow[4] = {0.f, 0.f, 0.f, 0.f};
  const float sc = 0.07216878364870323f;   // 1/sqrt(192)
  char* Pwv = Pl + w * 1024;

  const char* ksrc = (const char*)kcb + (long)b * SS * 1152;
  const char* vsrc = (const char*)kct + (long)b * 32 * 32768;
  const int smax = 2 * qt + 1;

  for (int st = 0; st <= smax; ++st) {
#pragma unroll
    for (int i = 0; i < 9; ++i) {
      int off = (w + i * 4) * 1024 + l * 16;
      gload16(ksrc + off, Kl + off);
    }
#pragma unroll
    for (int i = 0; i < 8; ++i) {
      int off = (w + i * 4) * 1024 + l * 16;
      gload16(vsrc + off, Vl + off);
    }
    __syncthreads();

    // QK^T
    f32x4 sa[2] = {};
    __builtin_amdgcn_s_setprio(1);
#pragma unroll
    for (int ks = 0; ks < 18; ++ks) {
#pragma unroll
      for (int n = 0; n < 2; ++n) {
        int kv = n * 16 + lo;
        bhalf8 kf = *(const bhalf8*)(Kl + kv * 1152 + (((ks * 4 + hi) ^ (kv & 7)) << 4));
        sa[n] = __builtin_amdgcn_mfma_f32_16x16x32_bf16(qf[ks], kf, sa[n], 0, 0, 0);
      }
    }
    __builtin_amdgcn_s_setprio(0);
    // scale + causal mask
    if (st >= 2 * qt) {
      const int kv0 = st * 32;
#pragma unroll
      for (int n = 0; n < 2; ++n) {
        int kvg = kv0 + n * 16 + lo;
#pragma unroll
        for (int r = 0; r < 4; ++r) {
          int qg = qt * 64 + w * 16 + hi * 4 + r;
          sa[n][r] = (kvg > qg) ? -1e30f : sa[n][r] * sc;
        }
      }
    } else {
#pragma unroll
      for (int n = 0; n < 2; ++n)
#pragma unroll
        for (int r = 0; r < 4; ++r) sa[n][r] *= sc;
    }
    // row max
    float pmax[4];
#pragma unroll
    for (int r = 0; r < 4; ++r) {
      float v = fmaxf(sa[0][r], sa[1][r]);
      v = fmaxf(v, __shfl_xor(v, 1));
      v = fmaxf(v, __shfl_xor(v, 2));
      v = fmaxf(v, __shfl_xor(v, 4));
      v = fmaxf(v, __shfl_xor(v, 8));
      pmax[r] = v;
    }
    // defer-max rescale (THR=8)
    bool need = false;
#pragma unroll
    for (int r = 0; r < 4; ++r) need |= (pmax[r] > mrow[r] + 8.f);
    if (__any(need)) {
#pragma unroll
      for (int r = 0; r < 4; ++r) {
        float mn = fmaxf(mrow[r], pmax[r]);
        float fac = __expf(mrow[r] - mn);
        mrow[r] = mn;
        lrow[r] *= fac;
#pragma unroll
        for (int nv = 0; nv < 32; ++nv) po[nv][r] *= fac;
      }
    }
    // P = exp(S - m), row sums
    float rs[4] = {0.f, 0.f, 0.f, 0.f};
#pragma unroll
    for (int n = 0; n < 2; ++n)
#pragma unroll
      for (int r = 0; r < 4; ++r) {
        float p = __expf(sa[n][r] - mrow[r]);
        sa[n][r] = p;
        rs[r] += p;
      }
#pragma unroll
    for (int r = 0; r < 4; ++r) {
      float v = rs[r];
      v += __shfl_xor(v, 1); v += __shfl_xor(v, 2);
      v += __shfl_xor(v, 4); v += __shfl_xor(v, 8);
      lrow[r] += v;
    }
    // P -> bf16 -> wave-private LDS
#pragma unroll
    for (int n = 0; n < 2; ++n)
#pragma unroll
      for (int r = 0; r < 4; ++r) {
        int q = hi * 4 + r, kv = n * 16 + lo;
        *(unsigned short*)(Pwv + q * 64 + ((kv * 2) ^ ((q & 3) << 4))) = f2b(sa[n][r]);
      }
    // PV
    bhalf8 pa = *(const bhalf8*)(Pwv + lo * 64 + ((hi * 16) ^ ((lo & 3) << 4)));
    __builtin_amdgcn_s_setprio(1);
#pragma unroll
    for (int nv = 0; nv < 32; ++nv) {
      int vc = nv * 16 + lo;
      bhalf8 vb = *(const bhalf8*)(Vl + vc * 64 + ((hi ^ ((vc >> 1) & 3)) << 4));
      po[nv] = __builtin_amdgcn_mfma_f32_16x16x32_bf16(pa, vb, po[nv], 0, 0, 0);
    }
    __builtin_amdgcn_s_setprio(0);
    __syncthreads();
    ksrc += 36864; vsrc += 32768;
  }

  // epilogue
  unsigned short* orow = omid + ((long)h * NT + b * SS + qt * 64) * 512;
  float inv[4];
#pragma unroll
  for (int r = 0; r < 4; ++r) inv[r] = 1.f / lrow[r];
#pragma unroll
  for (int nv = 0; nv < 32; ++nv)
#pragma unroll
    for (int r = 0; r < 4; ++r) {
      int q = w * 16 + hi * 4 + r;
      orow[(long)q * 512 + nv * 16 + lo] = f2b(po[nv][r] * inv[r]);
    }
}

// ---------------- launch ----------------
extern "C" void kernel_launch(void* const* d_in, const int* in_sizes, int n_in,
                              void* d_out, int out_size, void* d_ws, size_t ws_size,
                              hipStream_t stream) {
  const float* x        = (const float*)d_in[0];
  const float* wq_a_w   = (const float*)d_in[2];
  const float* wq_a_b   = (const float*)d_in[3];
  const float* q_norm_w = (const float*)d_in[4];
  const float* wq_b_w   = (const float*)d_in[5];
  const float* wq_b_b   = (const float*)d_in[6];
  const float* wkv_a_w  = (const float*)d_in[7];
  const float* wkv_a_b  = (const float*)d_in[8];
  const float* kv_norm_w= (const float*)d_in[9];
  const float* wk_b_w   = (const float*)d_in[10];
  const float* wo_w     = (const float*)d_in[11];
  const float* wo_bias  = (const float*)d_in[12];
  const float* cosT     = (const float*)d_in[13];
  const float* sinT     = (const float*)d_in[14];
  float* out = (float*)d_out;

  char* W = (char*)d_ws;
  // core live-through-flash buffers
  unsigned short* kcatb  = (unsigned short*)(W + 0);          // 2.36 MB [B*S][576] swz
  unsigned short* kcatT  = (unsigned short*)(W + 2359296);    // 2.10 MB [B][32][512][32] swz
  unsigned short* qcat   = (unsigned short*)(W + 4456448);    // 37.75 MB [16][NT][576]
  unsigned short* o_mid  = (unsigned short*)(W + 42205184);   // 33.55 MB [16][NT][512]
  // pre-flash aliases in qcat region — ALL dead before q_b writes qcat pe cols:
  unsigned short* xb     = (unsigned short*)(W + 4456448);    // 8.39 MB (dead after qkv_a)
  unsigned short* wqa_b  = (unsigned short*)(W + 12845056);   // 6.29 MB } contiguous: combined
  unsigned short* wkva_b = (unsigned short*)(W + 19136512);   // 2.36 MB } B of 2112 rows
  unsigned short* kv_b16 = (unsigned short*)(W + 21495808);   // 2.36 MB (dead after rmsnorm_kv)
  // pre-flash aliases in o_mid region (dead before flash writes o_mid)
  unsigned short* qb     = (unsigned short*)(W + 42205184);   // 12.58 MB [NT][3072]
  unsigned short* wkT_b  = (unsigned short*)(W + 54788096);   // 2.10 MB
  unsigned short* qn_b16 = (unsigned short*)(W + 56885248);   // 6.29 MB
  unsigned short* wqb_b  = (unsigned short*)(W + 63176704);   // 9.44 MB
  unsigned short* qnb    = (unsigned short*)(W + 72617984);   // 6.29 MB (end 78,909,440)
  // post-flash aliases in qcat region (qcat dead after flash)
  unsigned short* wkb_b  = (unsigned short*)(W + 4456448);    // 4.19 MB
  unsigned short* ohead  = (unsigned short*)(W + 8650752);    // 8.39 MB [NT][2048]
  unsigned short* wo_b16 = (unsigned short*)(W + 17039360);   // 8.39 MB

  // fused conversions (xb, wqa, wkva, wkT); wqb converted later
  cvtall_k<<<9344, 256, 0, stream>>>(x, xb, wq_a_w, wqa_b, wkv_a_w, wkva_b, wk_b_w, wkT_b);

  // combined q_a + kv_a: [qn_b16 | kv_b16] = x @ [wqa; wkva]^T  (bf16 outs, XCD swz)
  gemm64<0,0,1,1><<<dim3(544, 1, 1), 256, 0, stream>>>(
      xb, DIM, 0, wqa_b, DIM, 0, qn_b16, QR, 0, NT, QR + 576, DIM, wq_a_b,
      nullptr, nullptr, nullptr, kv_b16, wkv_a_b);

  // kv chain: rmsnorm(cols 0..511) + rope_k(cols 512..575) fused, then V^T build
  rmsnorm_k<1,1><<<NT, 256, 0, stream>>>(kv_b16, 576, kcatb, 576, kv_norm_w, KVR, cosT, sinT);
  kcT_k<<<4096, 256, 0, stream>>>(kcatb, kcatT);

  // q path
  rmsnorm_k<0,0><<<NT, 256, 0, stream>>>(qn_b16, QR, qnb, QR, q_norm_w, QR, nullptr, nullptr);
  cvt_k<<<4608, 256, 0, stream>>>(wq_b_w, wqb_b, (long)3072 * QR / 4);
  // q_b: qb = qnb @ wq_b^T (bf16); pe windows rope'd into qcat cols 512..575 (XCD swz)
  gemm64<1,1,0,1><<<dim3(768, 1, 1), 256, 0, stream>>>(
      qnb, QR, 0, wqb_b, QR, 0, qb, 3072, 0, NT, 3072, QR, wq_b_b,
      qcat, cosT, sinT, nullptr, nullptr);

  // q_abs for all 16 heads: qcat[z][:, :512] = q_nope_z @ wkT[z]^T  (128x128 path)
  gemm_mfma<1><<<dim3(4, NT/128, 16), 256, 0, stream>>>(
      qb, 3072, QKD, wkT_b, DN, (long)KVR * DN,
      qcat, 576, (long)NT * 576, NT, KVR, DN, nullptr);

  // fused attention, all heads, one dispatch (flat-descending qt, dispatch backfill)
  flash_k<<<512, 256, 0, stream>>>(qcat, kcatb, kcatT, o_mid);

  // post-flash conversions (wkb, wo) in one kernel  [qcat dead]
  cvt2_k<<<6144, 256, 0, stream>>>(wk_b_w, wkb_b, wo_w, wo_b16);

  // V-absorb: ohead[:, z*128..] = o_mid[z] @ wkv_b_v[z]^T  (64x128 tiles, z-grid)
  gemm64<1,0,0,0><<<dim3(1, NT/64, 16), 256, 0, stream>>>(
      o_mid, KVR, (long)NT * KVR,
      wkb_b + (long)DN * KVR, KVR, (long)256 * KVR,
      ohead, HH * DV, DV, NT, DV, KVR, nullptr,
      nullptr, nullptr, nullptr, nullptr, nullptr);

  // out = o_head @ wo^T + b (fp32, XCD swz)
  gemm64<0,0,0,1><<<dim3(512, 1, 1), 256, 0, stream>>>(
      ohead, 2048, 0, wo_b16, 2048, 0, out, DIM, 0, NT, DIM, 2048, wo_bias,
      nullptr, nullptr, nullptr, nullptr, nullptr);
}

// Round 17
// 328.981 us; speedup vs baseline: 1.3107x; 1.0059x over previous
//
#include <hip/hip_runtime.h>
#include <hip/hip_bf16.h>
#include <math.h>

#define BB 2
#define SS 1024
#define DIM 2048
#define HH 16
#define QR 1536
#define KVR 512
#define DN 128
#define DR 64
#define DV 128
#define QKD 192
#define NT (BB*SS)

typedef __attribute__((ext_vector_type(8))) short bhalf8;
typedef __attribute__((ext_vector_type(4))) float f32x4;

__device__ __forceinline__ unsigned short f2b(float f) {
  union { float f; unsigned u; } v; v.f = f;
  unsigned r = v.u + 0x7fffu + ((v.u >> 16) & 1u);
  return (unsigned short)(r >> 16);
}
__device__ __forceinline__ float b2f(unsigned short h) {
  union { unsigned u; float f; } v; v.u = ((unsigned)h) << 16;
  return v.f;
}

__device__ __forceinline__ void gload16(const void* g, void* l) {
  __builtin_amdgcn_global_load_lds((const __attribute__((address_space(1))) void*)g,
                                   (__attribute__((address_space(3))) void*)l, 16, 0, 0);
}

// ---------------- fused conversions: xb, wqa, wkva, wqb, wkT ----------------
__global__ void cvtall_k(const float* __restrict__ x,     unsigned short* __restrict__ xb,
                         const float* __restrict__ wqa,   unsigned short* __restrict__ wqab,
                         const float* __restrict__ wkva,  unsigned short* __restrict__ wkvab,
                         const float* __restrict__ wqb,   unsigned short* __restrict__ wqbb,
                         const float* __restrict__ wk,    unsigned short* __restrict__ wkT)
{
  long i = (long)blockIdx.x * 256 + threadIdx.x;
  const float* in; unsigned short* out; long j;
  if (i < 1048576)      { in = x;    out = xb;    j = i; }
  else if (i < 1835008) { in = wqa;  out = wqab;  j = i - 1048576; }
  else if (i < 2129920) { in = wkva; out = wkvab; j = i - 1835008; }
  else if (i < 3309568) { in = wqb;  out = wqbb;  j = i - 2129920; }
  else {
    j = i - 3309568;
    if (j >= 262144) return;
    long e = j * 4;
    int d = (int)(e & 127), c = (int)((e >> 7) & 511), h = (int)(e >> 16);
    ushort4 o;
    o.x = f2b(wk[((long)h * 256 + d + 0) * 512 + c]);
    o.y = f2b(wk[((long)h * 256 + d + 1) * 512 + c]);
    o.z = f2b(wk[((long)h * 256 + d + 2) * 512 + c]);
    o.w = f2b(wk[((long)h * 256 + d + 3) * 512 + c]);
    ((ushort4*)wkT)[j] = o;
    return;
  }
  float4 v = ((const float4*)in)[j];
  ushort4 o; o.x = f2b(v.x); o.y = f2b(v.y); o.z = f2b(v.z); o.w = f2b(v.w);
  ((ushort4*)out)[j] = o;
}

// ---------------- fused post-flash conversions: wkb, wo ----------------
__global__ void cvt2_k(const float* __restrict__ wk, unsigned short* __restrict__ wkb,
                       const float* __restrict__ wo, unsigned short* __restrict__ wob)
{
  long i = (long)blockIdx.x * 256 + threadIdx.x;
  const float* in; unsigned short* out; long j;
  if (i < 524288) { in = wk; out = wkb; j = i; }
  else            { in = wo; out = wob; j = i - 524288; if (j >= 1048576) return; }
  float4 v = ((const float4*)in)[j];
  ushort4 o; o.x = f2b(v.x); o.y = f2b(v.y); o.z = f2b(v.z); o.w = f2b(v.w);
  ((ushort4*)out)[j] = o;
}

// V^T tile-major: kt[b][st(32)][vc][kv'] with kv' = kvl ^ (((vc>>1)&3)<<3)
__global__ void kcT_k(const unsigned short* __restrict__ kc, unsigned short* __restrict__ kt) {
  int idx = blockIdx.x * 256 + threadIdx.x;    // 2*512*1024
  int t = idx & 1023, c = (idx >> 10) & 511, b = idx >> 19;
  int csrc = c ^ ((t & 7) << 3);
  int kvd  = (t & 31) ^ (((c >> 1) & 3) << 3);
  kt[(((long)b * 32 + (t >> 5)) * 512 + c) * 32 + kvd] =
      kc[((long)b * SS + t) * 576 + csrc];
}

// ---------------- MFMA GEMM 64x128 tile (high-occupancy variant) ----------------
// XSWZ=1: 1D grid, XCD-chunked decode.  SPLIT=1: bf16 outputs qn (ld QR) / kv (ld 576).
template<int OBF, int ROPE, int SPLIT, int XSWZ>
__global__ __launch_bounds__(256) void gemm64(
    const unsigned short* __restrict__ A, int lda, long sA,
    const unsigned short* __restrict__ B, int ldb, long sB,
    void* __restrict__ C, int ldc, long sC,
    int M, int N, int K, const float* __restrict__ bias,
    unsigned short* __restrict__ qcat, const float* __restrict__ cosT,
    const float* __restrict__ sinT,
    unsigned short* __restrict__ C2, const float* __restrict__ bias2)
{
  int bx, by;
  const int bz = blockIdx.z;
  if (XSWZ) {
    int nby = M >> 6;
    int idx = (blockIdx.x & 7) * (gridDim.x >> 3) + (blockIdx.x >> 3);
    bx = idx / nby;
    by = idx - bx * nby;
  } else {
    bx = blockIdx.x; by = blockIdx.y;
  }
  const int m0 = by * 64, n0 = bx * 128;
  A += (long)bz * sA;
  B += (long)bz * sB;

  __shared__ unsigned short As[2048];
  __shared__ unsigned short Bs[4096];
  const int tid = threadIdx.x, l = tid & 63, w = tid >> 6;
  const int rA = l >> 2;
  const int c8 = (((l & 3) ^ ((l >> 2) & 3)) << 3);

  f32x4 acc[8] = {};

  const unsigned short* Ab0 = A + (long)(m0 + w * 16 + rA) * lda + c8;
  int nb0 = n0 + w * 16 + rA;      if (nb0 > N - 1) nb0 = N - 1;
  int nb1 = n0 + 64 + w * 16 + rA; if (nb1 > N - 1) nb1 = N - 1;
  const unsigned short* Bb0 = B + (long)nb0 * ldb + c8;
  const unsigned short* Bb1 = B + (long)nb1 * ldb + c8;

  const int ko = (((l >> 4) ^ (l & 3)) << 3);

  for (int k0 = 0; k0 < K; k0 += 32) {
    gload16(Ab0 + k0, &As[w * 512]);
    gload16(Bb0 + k0, &Bs[w * 512]);
    gload16(Bb1 + k0, &Bs[(w + 4) * 512]);
    __syncthreads();
    bhalf8 af = *(const bhalf8*)&As[(w * 16 + (l & 15)) * 32 + ko];
    bhalf8 bv[8];
#pragma unroll
    for (int n = 0; n < 8; ++n)
      bv[n] = *(const bhalf8*)&Bs[(n * 16 + (l & 15)) * 32 + ko];
#pragma unroll
    for (int n = 0; n < 8; ++n)
      acc[n] = __builtin_amdgcn_mfma_f32_16x16x32_bf16(af, bv[n], acc[n], 0, 0, 0);
    __syncthreads();
  }

  const int ro = (l >> 4) << 2;
  const int co = l & 15;
#pragma unroll
  for (int r = 0; r < 4; ++r) {
    int row = m0 + w * 16 + ro + r;
    float v[8];
#pragma unroll
    for (int n = 0; n < 8; ++n) {
      int col = n0 + n * 16 + co;
      float bv2 = 0.f;
      if (SPLIT) bv2 = (col < QR) ? bias[col] : ((col < QR + 576) ? bias2[col - QR] : 0.f);
      else if (bias && col < N) bv2 = bias[col];
      v[n] = acc[n][r] + bv2;
    }
    if (ROPE) {
      int s = row & (SS - 1);
#pragma unroll
      for (int n = 0; n < 8; ++n) {
        int col0 = n0 + n * 16;
        int cm0 = col0 % 192;
        if (cm0 < 128) {
          ((unsigned short*)C)[(long)row * ldc + col0 + co] = f2b(v[n]);
        } else if (cm0 == 128 || cm0 == 144) {
          int d = cm0 - 128 + co;
          float cl = cosT[s * DR + d],      sl = sinT[s * DR + d];
          float ch = cosT[s * DR + d + 32], sh = sinT[s * DR + d + 32];
          float o_lo = v[n] * cl - v[n + 2] * sl;
          float o_hi = v[n + 2] * ch + v[n] * sh;
          unsigned short* qp = qcat + ((long)(col0 / 192) * NT + row) * 576 + 512;
          qp[d]      = f2b(o_lo);
          qp[d + 32] = f2b(o_hi);
        }
      }
    } else if (SPLIT) {
#pragma unroll
      for (int n = 0; n < 8; ++n) {
        int col = n0 + n * 16 + co;
        if (col < QR)            ((unsigned short*)C)[(long)row * ldc + col] = f2b(v[n]);
        else if (col < QR + 576) C2[(long)row * 576 + (col - QR)] = f2b(v[n]);
      }
    } else {
#pragma unroll
      for (int n = 0; n < 8; ++n) {
        int col = n0 + n * 16 + co;
        if (col < N) {
          long off = (long)bz * sC + (long)row * ldc + col;
          if (OBF) ((unsigned short*)C)[off] = f2b(v[n]);
          else     ((float*)C)[off] = v[n];
        }
      }
    }
  }
}

// ---------------- fused RMSNorm (q rows + kv rows in one dispatch) ----------------
// blocks 0..NT-1: q rows (qn_b16 -> qnb, width QR).
// blocks NT..2NT-1: kv rows (kv_b16 -> kcatb, width KVR, swizzled, + rope cols 512..575).
__global__ void rmsboth_k(const unsigned short* __restrict__ qn, unsigned short* __restrict__ qo,
                          const float* __restrict__ qw,
                          const unsigned short* __restrict__ kv, unsigned short* __restrict__ ko,
                          const float* __restrict__ kw,
                          const float* __restrict__ cosT, const float* __restrict__ sinT) {
  long bidx = blockIdx.x;
  if (bidx < NT) {
    const unsigned short* x = qn + bidx * QR;
    unsigned short* y = qo + bidx * QR;
    float ss = 0.f;
    for (int i = threadIdx.x; i < QR; i += 256) { float u = b2f(x[i]); ss += u * u; }
    for (int o = 32; o > 0; o >>= 1) ss += __shfl_down(ss, o);
    __shared__ float red[4];
    int lane = threadIdx.x & 63, wid = threadIdx.x >> 6;
    if (lane == 0) red[wid] = ss;
    __syncthreads();
    float r = rsqrtf((red[0] + red[1] + red[2] + red[3]) / (float)QR + 1e-6f);
    for (int i = threadIdx.x; i < QR; i += 256) y[i] = f2b(b2f(x[i]) * r * qw[i]);
  } else {
    long row = bidx - NT;
    const unsigned short* x = kv + row * 576;
    unsigned short* y = ko + row * 576;
    float ss = 0.f;
    for (int i = threadIdx.x; i < KVR; i += 256) { float u = b2f(x[i]); ss += u * u; }
    for (int o = 32; o > 0; o >>= 1) ss += __shfl_down(ss, o);
    __shared__ float red2[4];
    int lane = threadIdx.x & 63, wid = threadIdx.x >> 6;
    if (lane == 0) red2[wid] = ss;
    __syncthreads();
    float r = rsqrtf((red2[0] + red2[1] + red2[2] + red2[3]) / (float)KVR + 1e-6f);
    int sw = ((int)row & 7) << 3;
    for (int i = threadIdx.x; i < KVR; i += 256) y[i ^ sw] = f2b(b2f(x[i]) * r * kw[i]);
    if (threadIdx.x < 32) {
      int d = threadIdx.x;
      int s = (int)(row & (SS - 1));
      float x1 = b2f(x[512 + d]), x2 = b2f(x[512 + d + 32]);
      float c1 = cosT[s * DR + d],      s1 = sinT[s * DR + d];
      float c2 = cosT[s * DR + 32 + d], s2 = sinT[s * DR + 32 + d];
      y[(512 + d) ^ sw]      = f2b(x1 * c1 - x2 * s1);
      y[(512 + d + 32) ^ sw] = f2b(x2 * c2 + x1 * s2);
    }
  }
}

// ---------------- fused flash attention v5 (proven): staged K+V, defer-max ----------------
__global__ __launch_bounds__(256) void flash_k(
    const unsigned short* __restrict__ qcat,   // [16][NT][576] linear
    const unsigned short* __restrict__ kcb,    // [B][S][576]  col-swizzled ^((t&7)<<3)
    const unsigned short* __restrict__ kct,    // [B][32][512][32] tile-major, swizzled
    unsigned short* __restrict__ omid)         // [16][NT][512]
{
  __shared__ __align__(16) char lds[73728];
  char* Kl = lds;                // 36,864 B
  char* Vl = lds + 36864;        // 32,768 B
  char* Pl = lds + 69632;        //  4,096 B

  const int bid = blockIdx.x;
  const int qt = 15 - (bid >> 5);
  const int bh = bid & 31;
  const int b = bh & 1, h = bh >> 1;
  const int tid = threadIdx.x, l = tid & 63, w = tid >> 6;
  const int lo = l & 15, hi = l >> 4;

  const unsigned short* qrow =
      qcat + ((long)h * NT + b * SS + qt * 64 + w * 16 + lo) * 576 + hi * 8;
  bhalf8 qf[18];
#pragma unroll
  for (int ks = 0; ks < 18; ++ks) qf[ks] = *(const bhalf8*)(qrow + ks * 32);

  f32x4 po[32] = {};                  // O[q=hi*4+r][vc=nv*16+lo]
  float mrow[4] = {-1e30f, -1e30f, -1e30f, -1e30f};
  float lrow[4] = {0.f, 0.f, 0.f, 0.f};
  const float sc = 0.07216878364870323f;   // 1/sqrt(192)
  char* Pwv = Pl + w * 1024;

  const char* ksrc = (const char*)kcb + (long)b * SS * 1152;
  const char* vsrc = (const char*)kct + (long)b * 32 * 32768;
  const int smax = 2 * qt + 1;

  for (int st = 0; st <= smax; ++st) {
#pragma unroll
    for (int i = 0; i < 9; ++i) {
      int off = (w + i * 4) * 1024 + l * 16;
      gload16(ksrc + off, Kl + off);
    }
#pragma unroll
    for (int i = 0; i < 8; ++i) {
      int off = (w + i * 4) * 1024 + l * 16;
      gload16(vsrc + off, Vl + off);
    }
    __syncthreads();

    // QK^T
    f32x4 sa[2] = {};
    __builtin_amdgcn_s_setprio(1);
#pragma unroll
    for (int ks = 0; ks < 18; ++ks) {
#pragma unroll
      for (int n = 0; n < 2; ++n) {
        int kv = n * 16 + lo;
        bhalf8 kf = *(const bhalf8*)(Kl + kv * 1152 + (((ks * 4 + hi) ^ (kv & 7)) << 4));
        sa[n] = __builtin_amdgcn_mfma_f32_16x16x32_bf16(qf[ks], kf, sa[n], 0, 0, 0);
      }
    }
    __builtin_amdgcn_s_setprio(0);
    // scale + causal mask
    if (st >= 2 * qt) {
      const int kv0 = st * 32;
#pragma unroll
      for (int n = 0; n < 2; ++n) {
        int kvg = kv0 + n * 16 + lo;
#pragma unroll
        for (int r = 0; r < 4; ++r) {
          int qg = qt * 64 + w * 16 + hi * 4 + r;
          sa[n][r] = (kvg > qg) ? -1e30f : sa[n][r] * sc;
        }
      }
    } else {
#pragma unroll
      for (int n = 0; n < 2; ++n)
#pragma unroll
        for (int r = 0; r < 4; ++r) sa[n][r] *= sc;
    }
    // row max
    float pmax[4];
#pragma unroll
    for (int r = 0; r < 4; ++r) {
      float v = fmaxf(sa[0][r], sa[1][r]);
      v = fmaxf(v, __shfl_xor(v, 1));
      v = fmaxf(v, __shfl_xor(v, 2));
      v = fmaxf(v, __shfl_xor(v, 4));
      v = fmaxf(v, __shfl_xor(v, 8));
      pmax[r] = v;
    }
    // defer-max rescale (THR=8)
    bool need = false;
#pragma unroll
    for (int r = 0; r < 4; ++r) need |= (pmax[r] > mrow[r] + 8.f);
    if (__any(need)) {
#pragma unroll
      for (int r = 0; r < 4; ++r) {
        float mn = fmaxf(mrow[r], pmax[r]);
        float fac = __expf(mrow[r] - mn);
        mrow[r] = mn;
        lrow[r] *= fac;
#pragma unroll
        for (int nv = 0; nv < 32; ++nv) po[nv][r] *= fac;
      }
    }
    // P = exp(S - m), row sums
    float rs[4] = {0.f, 0.f, 0.f, 0.f};
#pragma unroll
    for (int n = 0; n < 2; ++n)
#pragma unroll
      for (int r = 0; r < 4; ++r) {
        float p = __expf(sa[n][r] - mrow[r]);
        sa[n][r] = p;
        rs[r] += p;
      }
#pragma unroll
    for (int r = 0; r < 4; ++r) {
      float v = rs[r];
      v += __shfl_xor(v, 1); v += __shfl_xor(v, 2);
      v += __shfl_xor(v, 4); v += __shfl_xor(v, 8);
      lrow[r] += v;
    }
    // P -> bf16 -> wave-private LDS
#pragma unroll
    for (int n = 0; n < 2; ++n)
#pragma unroll
      for (int r = 0; r < 4; ++r) {
        int q = hi * 4 + r, kv = n * 16 + lo;
        *(unsigned short*)(Pwv + q * 64 + ((kv * 2) ^ ((q & 3) << 4))) = f2b(sa[n][r]);
      }
    // PV
    bhalf8 pa = *(const bhalf8*)(Pwv + lo * 64 + ((hi * 16) ^ ((lo & 3) << 4)));
    __builtin_amdgcn_s_setprio(1);
#pragma unroll
    for (int nv = 0; nv < 32; ++nv) {
      int vc = nv * 16 + lo;
      bhalf8 vb = *(const bhalf8*)(Vl + vc * 64 + ((hi ^ ((vc >> 1) & 3)) << 4));
      po[nv] = __builtin_amdgcn_mfma_f32_16x16x32_bf16(pa, vb, po[nv], 0, 0, 0);
    }
    __builtin_amdgcn_s_setprio(0);
    __syncthreads();
    ksrc += 36864; vsrc += 32768;
  }

  // epilogue
  unsigned short* orow = omid + ((long)h * NT + b * SS + qt * 64) * 512;
  float inv[4];
#pragma unroll
  for (int r = 0; r < 4; ++r) inv[r] = 1.f / lrow[r];
#pragma unroll
  for (int nv = 0; nv < 32; ++nv)
#pragma unroll
    for (int r = 0; r < 4; ++r) {
      int q = w * 16 + hi * 4 + r;
      orow[(long)q * 512 + nv * 16 + lo] = f2b(po[nv][r] * inv[r]);
    }
}

// ---------------- launch ----------------
extern "C" void kernel_launch(void* const* d_in, const int* in_sizes, int n_in,
                              void* d_out, int out_size, void* d_ws, size_t ws_size,
                              hipStream_t stream) {
  const float* x        = (const float*)d_in[0];
  const float* wq_a_w   = (const float*)d_in[2];
  const float* wq_a_b   = (const float*)d_in[3];
  const float* q_norm_w = (const float*)d_in[4];
  const float* wq_b_w   = (const float*)d_in[5];
  const float* wq_b_b   = (const float*)d_in[6];
  const float* wkv_a_w  = (const float*)d_in[7];
  const float* wkv_a_b  = (const float*)d_in[8];
  const float* kv_norm_w= (const float*)d_in[9];
  const float* wk_b_w   = (const float*)d_in[10];
  const float* wo_w     = (const float*)d_in[11];
  const float* wo_bias  = (const float*)d_in[12];
  const float* cosT     = (const float*)d_in[13];
  const float* sinT     = (const float*)d_in[14];
  float* out = (float*)d_out;

  char* W = (char*)d_ws;
  // core live-through-flash buffers
  unsigned short* kcatb  = (unsigned short*)(W + 0);          // 2.36 MB [B*S][576] swz
  unsigned short* kcatT  = (unsigned short*)(W + 2359296);    // 2.10 MB [B][32][512][32] swz
  unsigned short* qcat   = (unsigned short*)(W + 4456448);    // 37.75 MB [16][NT][576]
  unsigned short* o_mid  = (unsigned short*)(W + 42205184);   // 33.55 MB [16][NT][512]
  // pre-flash aliases in qcat region — ALL dead before q_b writes qcat pe cols:
  unsigned short* xb     = (unsigned short*)(W + 4456448);    // 8.39 MB (dead after qkv_a)
  unsigned short* wqa_b  = (unsigned short*)(W + 12845056);   // 6.29 MB } contiguous: combined
  unsigned short* wkva_b = (unsigned short*)(W + 19136512);   // 2.36 MB } B of 2112 rows
  unsigned short* kv_b16 = (unsigned short*)(W + 21495808);   // 2.36 MB (dead after rmsboth)
  // pre-flash aliases in o_mid region (dead before flash writes o_mid)
  unsigned short* qb     = (unsigned short*)(W + 42205184);   // 12.58 MB [NT][3072]
  unsigned short* wkT_b  = (unsigned short*)(W + 54788096);   // 2.10 MB
  unsigned short* qn_b16 = (unsigned short*)(W + 56885248);   // 6.29 MB
  unsigned short* wqb_b  = (unsigned short*)(W + 63176704);   // 9.44 MB
  unsigned short* qnb    = (unsigned short*)(W + 72617984);   // 6.29 MB (end 78,909,440)
  // post-flash aliases in qcat region (qcat dead after flash)
  unsigned short* wkb_b  = (unsigned short*)(W + 4456448);    // 4.19 MB
  unsigned short* ohead  = (unsigned short*)(W + 8650752);    // 8.39 MB [NT][2048]
  unsigned short* wo_b16 = (unsigned short*)(W + 17039360);   // 8.39 MB

  // fused conversions (xb, wqa, wkva, wqb, wkT)
  cvtall_k<<<13952, 256, 0, stream>>>(x, xb, wq_a_w, wqa_b, wkv_a_w, wkva_b,
                                      wq_b_w, wqb_b, wk_b_w, wkT_b);

  // combined q_a + kv_a: [qn_b16 | kv_b16] = x @ [wqa; wkva]^T  (bf16 outs, XCD swz)
  gemm64<0,0,1,1><<<dim3(544, 1, 1), 256, 0, stream>>>(
      xb, DIM, 0, wqa_b, DIM, 0, qn_b16, QR, 0, NT, QR + 576, DIM, wq_a_b,
      nullptr, nullptr, nullptr, kv_b16, wkv_a_b);

  // both rmsnorms (q + kv with fused rope_k) in one dispatch
  rmsboth_k<<<2 * NT, 256, 0, stream>>>(qn_b16, qnb, q_norm_w,
                                        kv_b16, kcatb, kv_norm_w, cosT, sinT);
  kcT_k<<<4096, 256, 0, stream>>>(kcatb, kcatT);

  // q_b: qb = qnb @ wq_b^T (bf16); pe windows rope'd into qcat cols 512..575 (XCD swz)
  gemm64<1,1,0,1><<<dim3(768, 1, 1), 256, 0, stream>>>(
      qnb, QR, 0, wqb_b, QR, 0, qb, 3072, 0, NT, 3072, QR, wq_b_b,
      qcat, cosT, sinT, nullptr, nullptr);

  // q_abs for all 16 heads: qcat[z][:, :512] = q_nope_z @ wkT[z]^T  (64x128 tiles)
  gemm64<1,0,0,0><<<dim3(4, NT/64, 16), 256, 0, stream>>>(
      qb, 3072, QKD, wkT_b, DN, (long)KVR * DN,
      qcat, 576, (long)NT * 576, NT, KVR, DN, nullptr,
      nullptr, nullptr, nullptr, nullptr, nullptr);

  // fused attention, all heads, one dispatch (flat-descending qt, dispatch backfill)
  flash_k<<<512, 256, 0, stream>>>(qcat, kcatb, kcatT, o_mid);

  // post-flash conversions (wkb, wo) in one kernel  [qcat dead]
  cvt2_k<<<6144, 256, 0, stream>>>(wk_b_w, wkb_b, wo_w, wo_b16);

  // V-absorb: ohead[:, z*128..] = o_mid[z] @ wkv_b_v[z]^T  (64x128 tiles, z-grid)
  gemm64<1,0,0,0><<<dim3(1, NT/64, 16), 256, 0, stream>>>(
      o_mid, KVR, (long)NT * KVR,
      wkb_b + (long)DN * KVR, KVR, (long)256 * KVR,
      ohead, HH * DV, DV, NT, DV, KVR, nullptr,
      nullptr, nullptr, nullptr, nullptr, nullptr);

  // out = o_head @ wo^T + b (fp32, XCD swz)
  gemm64<0,0,0,1><<<dim3(512, 1, 1), 256, 0, stream>>>(
      ohead, 2048, 0, wo_b16, 2048, 0, out, DIM, 0, NT, DIM, 2048, wo_bias,
      nullptr, nullptr, nullptr, nullptr, nullptr);
}